// Round 11
// baseline (1204.189 us; speedup 1.0000x reference)
//
#include <hip/hip_runtime.h>
#include <cstdint>

#define S_LEN 3600
#define DMODEL 1536
#define LCTX 512
#define NH 12
#define HDIM 128
#define FFND 8960
#define SPAD_SELF 3648

typedef short v8s __attribute__((ext_vector_type(8)));
typedef float v4f __attribute__((ext_vector_type(4)));
typedef unsigned short u16b;
typedef unsigned int u32b;

#define AS1 __attribute__((address_space(1)))
#define AS3 __attribute__((address_space(3)))

__device__ __forceinline__ void gl_lds16(const void* g, void* l){
  __builtin_amdgcn_global_load_lds((AS1 const void*)g, (AS3 void*)l, 16, 0, 0);
}

__device__ __forceinline__ u16b f2b(float f){
  union { float f; u32b i; } x; x.f = f;
  u32b r = x.i + 0x7fffu + ((x.i >> 16) & 1u);
  return (u16b)(r >> 16);
}

__device__ __forceinline__ u32b cvtpk(float a, float b){
  u32b r;
  asm("v_cvt_pk_bf16_f32 %0, %1, %2" : "=v"(r) : "v"(a), "v"(b));
  return r;
}

__device__ __forceinline__ int swz4(int row){ return (row ^ (row >> 2)) & 3; }

// bijective XCD swizzle (m204)
__device__ __forceinline__ int xcd_swz(int orig, int nwg){
  int q8 = nwg >> 3, r8 = nwg & 7;
  int xcd = orig & 7, idx = orig >> 3;
  return (xcd < r8 ? xcd * (q8 + 1) : r8 * (q8 + 1) + (xcd - r8) * q8) + idx;
}

// ---------------- small elementwise kernels ----------------
__global__ void add_vec(const float* __restrict__ a, const float* __restrict__ b,
                        float* __restrict__ o, int n){
  int i = blockIdx.x * 256 + threadIdx.x;
  if (i < n) o[i] = a[i] + b[i];
}

__global__ void f2b_kernel(const float* __restrict__ in, u16b* __restrict__ out, int n){
  int i = blockIdx.x * 256 + threadIdx.x;
  if (i < n) out[i] = f2b(in[i]);
}

// ---------------- fused transpose-convert of all weights ----------------
struct WJob { const float* W; u16b* WT; int K; int N; int t0; };
struct WJobs { WJob j[10]; };

__global__ __launch_bounds__(256) void wconv(WJobs jobs){
  __shared__ float tile[32][33];
  int b = blockIdx.x;
  int ji = 0;
  #pragma unroll
  for (int i = 0; i < 10; ++i) if (b >= jobs.j[i].t0) ji = i;
  WJob jb = jobs.j[ji];
  int rel = b - jb.t0;
  int ntn = jb.N / 32;
  int k0 = (rel / ntn) * 32, n0 = (rel % ntn) * 32;
  int tx = threadIdx.x & 31, ty = threadIdx.x >> 5;
  #pragma unroll
  for (int r = ty; r < 32; r += 8) tile[r][tx] = jb.W[(size_t)(k0 + r) * jb.N + n0 + tx];
  __syncthreads();
  #pragma unroll
  for (int r = ty; r < 32; r += 8) jb.WT[(size_t)(n0 + r) * jb.K + k0 + tx] = f2b(tile[tx][r]);
}

// ---------------- per-head V transpose ----------------
__global__ __launch_bounds__(256) void vtrans(const u16b* __restrict__ V,
                                              u16b* __restrict__ Vt,
                                              int S, int Spad){
  __shared__ u16b t[32][136];
  int h = blockIdx.y, kb = blockIdx.x * 32, tid = threadIdx.x;
  int row = tid >> 3, ch = tid & 7;
  int key = kb + row;
  if (key < S){
    float4 a = *(const float4*)(V + (size_t)key * DMODEL + h * HDIM + ch * 16);
    float4 b = *(const float4*)(V + (size_t)key * DMODEL + h * HDIM + ch * 16 + 8);
    *(float4*)&t[row][ch * 16] = a;
    *(float4*)&t[row][ch * 16 + 8] = b;
  } else {
    float4 z = {0.f, 0.f, 0.f, 0.f};
    *(float4*)&t[row][ch * 16] = z;
    *(float4*)&t[row][ch * 16 + 8] = z;
  }
  __syncthreads();
  int hd = tid >> 1, kc = (tid & 1) * 16;
  u16b* dst = Vt + ((size_t)h * HDIM + hd) * Spad + kb + kc;
  #pragma unroll
  for (int e = 0; e < 16; e += 2){
    u32b pk = ((u32b)t[kc + e][hd]) | (((u32b)t[kc + e + 1][hd]) << 16);
    *(u32b*)(dst + e) = pk;
  }
}

// ---------------- LayerNorm (mod) -> bf16 ----------------
__global__ __launch_bounds__(256) void ln_mod(const float* __restrict__ X,
                                              const float* __restrict__ gamma,
                                              const float* __restrict__ beta,
                                              float gadd, u16b* __restrict__ out){
  int row = blockIdx.x;
  const float* xr = X + (size_t)row * DMODEL;
  int tid = threadIdx.x;
  float v[6]; float s1 = 0.f, s2 = 0.f;
  #pragma unroll
  for (int j = 0; j < 6; ++j){ v[j] = xr[tid + j * 256]; s1 += v[j]; s2 += v[j] * v[j]; }
  #pragma unroll
  for (int o = 1; o < 64; o <<= 1){ s1 += __shfl_xor(s1, o); s2 += __shfl_xor(s2, o); }
  __shared__ float red[8];
  int wid = tid >> 6, lane = tid & 63;
  if (!lane){ red[wid * 2] = s1; red[wid * 2 + 1] = s2; }
  __syncthreads();
  s1 = red[0] + red[2] + red[4] + red[6];
  s2 = red[1] + red[3] + red[5] + red[7];
  float mu = s1 / DMODEL;
  float var = s2 / DMODEL - mu * mu;
  float rstd = rsqrtf(var + 1e-6f);
  #pragma unroll
  for (int j = 0; j < 6; ++j){
    int c = tid + j * 256;
    out[(size_t)row * DMODEL + c] = f2b((v[j] - mu) * rstd * (gamma[c] + gadd) + beta[c]);
  }
}

// ---------------- fused: y = res + gate*(p0+p1+bias); h = LN(y)*gamma(+gadd)+beta ----------------
__global__ __launch_bounds__(256) void red2_ln(
    const float* __restrict__ p0, const float* __restrict__ p1,
    const float* __restrict__ res, const float* __restrict__ gate,
    const float* __restrict__ bias,
    const float* __restrict__ gamma, const float* __restrict__ beta, float gadd,
    float* __restrict__ yOut, u16b* __restrict__ hOut)
{
  int row = blockIdx.x, tid = threadIdx.x;
  size_t base = (size_t)row * DMODEL;
  float y[6]; float s1 = 0.f, s2 = 0.f;
  #pragma unroll
  for (int j = 0; j < 6; ++j){
    int c = tid + j * 256;
    float v = p0[base + c] + p1[base + c] + bias[c];
    if (gate) v *= gate[c];
    v += res[base + c];
    y[j] = v; s1 += v; s2 += v * v;
  }
  #pragma unroll
  for (int o = 1; o < 64; o <<= 1){ s1 += __shfl_xor(s1, o); s2 += __shfl_xor(s2, o); }
  __shared__ float red[8];
  int wid = tid >> 6, lane = tid & 63;
  if (!lane){ red[wid * 2] = s1; red[wid * 2 + 1] = s2; }
  __syncthreads();
  s1 = red[0] + red[2] + red[4] + red[6];
  s2 = red[1] + red[3] + red[5] + red[7];
  float mu = s1 / DMODEL;
  float var = s2 / DMODEL - mu * mu;
  float rstd = rsqrtf(var + 1e-6f);
  #pragma unroll
  for (int j = 0; j < 6; ++j){
    int c = tid + j * 256;
    yOut[base + c] = y[j];
    hOut[base + c] = f2b((y[j] - mu) * rstd * (gamma[c] + gadd) + beta[c]);
  }
}

// ---------------- RMSNorm (+optional RoPE) fp32 -> bf16 ----------------
__global__ __launch_bounds__(256) void rms_rope(const float* __restrict__ X,
                                                const float* __restrict__ w,
                                                const float* __restrict__ cosT,
                                                const float* __restrict__ sinT,
                                                float qmul,
                                                u16b* __restrict__ out){
  int row = blockIdx.x;
  const float* xr = X + (size_t)row * DMODEL;
  int tid = threadIdx.x;
  float2 v[3]; float ss = 0.f;
  #pragma unroll
  for (int j = 0; j < 3; ++j){
    v[j] = *(const float2*)(xr + 2 * (tid + j * 256));
    ss += v[j].x * v[j].x + v[j].y * v[j].y;
  }
  #pragma unroll
  for (int o = 1; o < 64; o <<= 1) ss += __shfl_xor(ss, o);
  __shared__ float red[4];
  int wid = tid >> 6, lane = tid & 63;
  if (!lane) red[wid] = ss;
  __syncthreads();
  ss = red[0] + red[1] + red[2] + red[3];
  float rstd = rsqrtf(ss / DMODEL + 1e-6f);
  #pragma unroll
  for (int j = 0; j < 3; ++j){
    int p = tid + j * 256;
    float xe = v[j].x * rstd * w[2 * p];
    float xo = v[j].y * rstd * w[2 * p + 1];
    float oe, oo;
    if (cosT){
      int d = p & 63;
      float c = cosT[row * 64 + d], sn = sinT[row * 64 + d];
      oe = xe * c - xo * sn; oo = xe * sn + xo * c;
    } else { oe = xe; oo = xo; }
    oe *= qmul; oo *= qmul;
    u32b packed = ((u32b)f2b(oe)) | (((u32b)f2b(oo)) << 16);
    *(u32b*)(out + (size_t)row * DMODEL + 2 * p) = packed;
  }
}

// ---------------- segment descriptors ----------------
struct Seg { const float* bias; float* outF; u16b* outB; };
struct Segs { Seg s[3]; };

// ---------------- 128x128 GEMM, 3-buffer counted-vmcnt pipeline ----------------
// EPI: 3 = gelu->bf16 (bias); 5 = split-K partial contiguous (outF + z*M*N);
//      6 = split-K partial two-pointer (z ? outF2 : outF)
template<int EPI>
__global__ __launch_bounds__(256, 2) void gemm_bt(
    const u16b* __restrict__ A, const u16b* __restrict__ BT,
    const float* __restrict__ bias, float* __restrict__ outF,
    float* __restrict__ outF2, u16b* __restrict__ outB,
    int M, int N, int K, int kLen)
{
  __shared__ char Ls[3][16384];
  const int tid = threadIdx.x, lane = tid & 63, wid = tid >> 6;
  const int nwg = gridDim.x * gridDim.y;
  const int swz = xcd_swz(blockIdx.x + gridDim.x * blockIdx.y, nwg);
  const int bm = (swz % gridDim.x) * 128, bn = (swz / gridDim.x) * 128;
  const int kbase = blockIdx.z * kLen;
  const int wm = (wid >> 1) * 64, wn = (wid & 1) * 64;
  v4f acc[4][4] = {};

  const u16b* pA[2]; const u16b* pB[2];
  #pragma unroll
  for (int c = 0; c < 2; ++c){
    int row = c * 64 + (tid >> 2);
    int col = (tid & 3) ^ swz4(row);
    pA[c] = A + (size_t)min(bm + row, M - 1) * K + kbase + col * 8;
    pB[c] = BT + (size_t)(bn + row) * K + kbase + col * 8;
  }
  auto stage = [&](int b){
    char* Lb = Ls[b];
    #pragma unroll
    for (int c = 0; c < 2; ++c){
      gl_lds16(pA[c], Lb + (c * 256 + tid) * 16);
      gl_lds16(pB[c], Lb + 8192 + (c * 256 + tid) * 16);
      pA[c] += 32; pB[c] += 32;
    }
  };

  const int chk = lane >> 4, qr = lane & 15;
  int offA[4], offB[4];
  #pragma unroll
  for (int f = 0; f < 4; ++f){
    int ra = wm + f * 16 + qr;
    offA[f] = ra * 64 + ((chk ^ swz4(ra)) * 16);
    int rb = wn + f * 16 + qr;
    offB[f] = 8192 + rb * 64 + ((chk ^ swz4(rb)) * 16);
  }

  const int nt = kLen / 32;
  stage(0); stage(1);
  int s = 0, sp = 2;
  for (int t = 0; t < nt; ++t){
    if (t + 1 < nt) asm volatile("s_waitcnt vmcnt(4)" ::: "memory");
    else            asm volatile("s_waitcnt vmcnt(0)" ::: "memory");
    __builtin_amdgcn_s_barrier();
    if (t + 2 < nt) stage(sp);
    char* Lb = Ls[s];
    v8s af[4], bfr[4];
    #pragma unroll
    for (int f = 0; f < 4; ++f){
      af[f] = *(const v8s*)(Lb + offA[f]);
      bfr[f] = *(const v8s*)(Lb + offB[f]);
    }
    __builtin_amdgcn_s_setprio(1);
    #pragma unroll
    for (int i = 0; i < 4; ++i)
      #pragma unroll
      for (int j = 0; j < 4; ++j)
        acc[i][j] = __builtin_amdgcn_mfma_f32_16x16x32_bf16(af[i], bfr[j], acc[i][j], 0, 0, 0);
    __builtin_amdgcn_s_setprio(0);
    s = (s == 2) ? 0 : s + 1;
    sp = (sp == 2) ? 0 : sp + 1;
  }
  const int rr = lane >> 4;
  float* op6 = (EPI == 6) ? (blockIdx.z ? outF2 : outF) : outF;
  #pragma unroll
  for (int i = 0; i < 4; ++i){
    #pragma unroll
    for (int j = 0; j < 4; ++j){
      int n = bn + wn + j * 16 + qr;
      float bv = (EPI == 3) ? bias[n] : 0.f;
      #pragma unroll
      for (int r = 0; r < 4; ++r){
        int m = bm + wm + i * 16 + rr * 4 + r;
        if (m < M){
          float val = acc[i][j][r] + bv;
          size_t idx = (size_t)m * N + n;
          if (EPI == 3){
            float t3 = val * val * val;
            float g = val / (1.f + __expf(-1.5957691216057308f * (val + 0.044715f * t3)));
            outB[idx] = f2b(g);
          } else if (EPI == 5){
            outF[(size_t)blockIdx.z * M * N + idx] = val;
          } else {
            op6[idx] = val;
          }
        }
      }
    }
  }
}

// ---------------- segmented 128^2 GEMM (QKV / ca K/V fused) ----------------
__global__ __launch_bounds__(256, 2) void gemm_seg(
    const u16b* __restrict__ A, const u16b* __restrict__ BT,
    Segs segs, int M, int N, int K)
{
  __shared__ char Ls[3][16384];
  const int tid = threadIdx.x, lane = tid & 63, wid = tid >> 6;
  const int nwg = gridDim.x * gridDim.y;
  const int swz = xcd_swz(blockIdx.x + gridDim.x * blockIdx.y, nwg);
  const int bm = (swz % gridDim.x) * 128, bn = (swz / gridDim.x) * 128;
  const int wm = (wid >> 1) * 64, wn = (wid & 1) * 64;
  v4f acc[4][4] = {};

  const u16b* pA[2]; const u16b* pB[2];
  #pragma unroll
  for (int c = 0; c < 2; ++c){
    int row = c * 64 + (tid >> 2);
    int col = (tid & 3) ^ swz4(row);
    pA[c] = A + (size_t)min(bm + row, M - 1) * K + col * 8;
    pB[c] = BT + (size_t)(bn + row) * K + col * 8;
  }
  auto stage = [&](int b){
    char* Lb = Ls[b];
    #pragma unroll
    for (int c = 0; c < 2; ++c){
      gl_lds16(pA[c], Lb + (c * 256 + tid) * 16);
      gl_lds16(pB[c], Lb + 8192 + (c * 256 + tid) * 16);
      pA[c] += 32; pB[c] += 32;
    }
  };

  const int chk = lane >> 4, qr = lane & 15;
  int offA[4], offB[4];
  #pragma unroll
  for (int f = 0; f < 4; ++f){
    int ra = wm + f * 16 + qr;
    offA[f] = ra * 64 + ((chk ^ swz4(ra)) * 16);
    int rb = wn + f * 16 + qr;
    offB[f] = 8192 + rb * 64 + ((chk ^ swz4(rb)) * 16);
  }

  const int nt = K / 32;
  stage(0); stage(1);
  int s = 0, sp = 2;
  for (int t = 0; t < nt; ++t){
    if (t + 1 < nt) asm volatile("s_waitcnt vmcnt(4)" ::: "memory");
    else            asm volatile("s_waitcnt vmcnt(0)" ::: "memory");
    __builtin_amdgcn_s_barrier();
    if (t + 2 < nt) stage(sp);
    char* Lb = Ls[s];
    v8s af[4], bfr[4];
    #pragma unroll
    for (int f = 0; f < 4; ++f){
      af[f] = *(const v8s*)(Lb + offA[f]);
      bfr[f] = *(const v8s*)(Lb + offB[f]);
    }
    __builtin_amdgcn_s_setprio(1);
    #pragma unroll
    for (int i = 0; i < 4; ++i)
      #pragma unroll
      for (int j = 0; j < 4; ++j)
        acc[i][j] = __builtin_amdgcn_mfma_f32_16x16x32_bf16(af[i], bfr[j], acc[i][j], 0, 0, 0);
    __builtin_amdgcn_s_setprio(0);
    s = (s == 2) ? 0 : s + 1;
    sp = (sp == 2) ? 0 : sp + 1;
  }
  const int seg = bn / 1536;
  const Seg sg = segs.s[seg];
  const int rr = lane >> 4;
  #pragma unroll
  for (int i = 0; i < 4; ++i){
    #pragma unroll
    for (int j = 0; j < 4; ++j){
      int nloc = bn - seg * 1536 + wn + j * 16 + qr;
      float bv = sg.bias[nloc];
      #pragma unroll
      for (int r = 0; r < 4; ++r){
        int m = bm + wm + i * 16 + rr * 4 + r;
        if (m < M){
          float val = acc[i][j][r] + bv;
          size_t idx = (size_t)m * 1536 + nloc;
          if (sg.outB) sg.outB[idx] = f2b(val);
          else sg.outF[idx] = val;
        }
      }
    }
  }
}

// ---------------- split-K x2 reduce: out = res? + gate? * (p0+p1+bias) ----------------
__global__ __launch_bounds__(256) void red2(const float* __restrict__ p0,
                                            const float* __restrict__ p1,
                                            const float* __restrict__ res,
                                            const float* __restrict__ gate,
                                            const float* __restrict__ bias,
                                            float* __restrict__ out, int total){
  int i4 = blockIdx.x * 256 + threadIdx.x;
  if (i4 * 4 >= total) return;
  int base = i4 * 4, n = base % DMODEL;
  float4 a = *(const float4*)(p0 + base);
  float4 b = *(const float4*)(p1 + base);
  float4 bv = *(const float4*)(bias + n);
  float gx = 1.f, gy = 1.f, gz = 1.f, gw = 1.f;
  if (gate){ float4 g = *(const float4*)(gate + n); gx = g.x; gy = g.y; gz = g.z; gw = g.w; }
  float rx = 0.f, ry = 0.f, rz = 0.f, rw = 0.f;
  if (res){ float4 r = *(const float4*)(res + base); rx = r.x; ry = r.y; rz = r.z; rw = r.w; }
  float4 o;
  o.x = rx + gx * (a.x + b.x + bv.x);
  o.y = ry + gy * (a.y + b.y + bv.y);
  o.z = rz + gz * (a.z + b.z + bv.z);
  o.w = rw + gw * (a.w + b.w + bv.w);
  *(float4*)(out + base) = o;
}

// ---------------- split-flash merge ----------------
__global__ __launch_bounds__(256) void merge_o(const float* __restrict__ op0,
                                               const float* __restrict__ op1,
                                               const float2* __restrict__ ml,
                                               u16b* __restrict__ outO, int Sq){
  int i4 = blockIdx.x * 256 + threadIdx.x;
  const int perRow = DMODEL / 4;
  if (i4 >= Sq * perRow) return;
  int row = i4 / perRow, c4 = (i4 % perRow) * 4;
  int h = c4 >> 7;
  float2 ml0 = ml[h * Sq + row];
  float2 ml1 = ml[NH * Sq + h * Sq + row];
  float M = fmaxf(ml0.x, ml1.x);
  float w0 = exp2f(ml0.x - M), w1 = exp2f(ml1.x - M);
  float inv = 1.f / (ml0.y * w0 + ml1.y * w1);
  float4 a = *(const float4*)(op0 + (size_t)row * DMODEL + c4);
  float4 b = *(const float4*)(op1 + (size_t)row * DMODEL + c4);
  u32b lo = ((u32b)f2b((a.x * w0 + b.x * w1) * inv)) | (((u32b)f2b((a.y * w0 + b.y * w1) * inv)) << 16);
  u32b hi = ((u32b)f2b((a.z * w0 + b.z * w1) * inv)) | (((u32b)f2b((a.w * w0 + b.w * w1) * inv)) << 16);
  uint2 w2; w2.x = lo; w2.y = hi;
  *(uint2*)(outO + (size_t)row * DMODEL + c4) = w2;
}

// ---------------- flash attention: Q-tile 128 (8 waves), KVBLK=64, key-split x2 ----------------
__global__ __launch_bounds__(512, 6) void flash_attn(
    const u16b* __restrict__ Q, const u16b* __restrict__ Kp,
    const u16b* __restrict__ Vt, u16b* __restrict__ O,
    float* __restrict__ op0, float* __restrict__ op1,
    float2* __restrict__ mlbuf,
    int Sq, int Sk, int ksplit, int Spad)
{
  __shared__ char KV[32768];     // K 16KB [64 keys][256B swz] | V 16KB [128 hd][128B swz]
  __shared__ char Pall[16384];   // 8 waves x 2KB
  const int tid = threadIdx.x, lane = tid & 63, wid = tid >> 6;
  const int h = blockIdx.y;
  const int z = blockIdx.z;
  const int kbeg = z * ksplit;
  const int kend = min(kbeg + ksplit, Sk);
  const int q0 = blockIdx.x * 128 + wid * 16;
  const int qq = lane & 15, cc = lane >> 4;
  char* Kb = KV; char* Vb = KV + 16384;
  char* Pb = Pall + wid * 2048;

  v8s qf[4];
  {
    int qrow = min(q0 + qq, Sq - 1);
    const u16b* qp = Q + (size_t)qrow * DMODEL + h * HDIM + cc * 8;
    #pragma unroll
    for (int ks = 0; ks < 4; ++ks) qf[ks] = *(const v8s*)(qp + ks * 32);
  }

  auto stage = [&](int kb0){
    #pragma unroll
    for (int c = 0; c < 2; ++c){
      int l = c * 512 + tid;
      int krow = l >> 4, kcol = (l & 15) ^ (krow & 7);
      gl_lds16(Kp + (size_t)min(kb0 + krow, Sk - 1) * DMODEL + h * HDIM + kcol * 8,
               Kb + l * 16);
      int vrow = l >> 3, vcol = (l & 7) ^ (vrow & 7);
      gl_lds16(Vt + ((size_t)h * HDIM + vrow) * Spad + kb0 + vcol * 8,
               Vb + l * 16);
    }
  };

  float mrun = -1e30f, lrun = 0.f;
  v4f oacc[8] = {};
  const int nt = (kend - kbeg + 63) >> 6;

  for (int t = 0; t < nt; ++t){
    int kb0 = kbeg + (t << 6);
    stage(kb0);
    __syncthreads();
    v4f sc[4];
    __builtin_amdgcn_s_setprio(1);
    #pragma unroll
    for (int sub = 0; sub < 4; ++sub){
      v4f sa = {0.f, 0.f, 0.f, 0.f};
      int row = sub * 16 + qq;
      #pragma unroll
      for (int ks = 0; ks < 4; ++ks){
        v8s kf = *(const v8s*)(Kb + row * 256 + (((ks * 4 + cc) ^ (row & 7)) * 16));
        sa = __builtin_amdgcn_mfma_f32_16x16x32_bf16(kf, qf[ks], sa, 0, 0, 0);
      }
      sc[sub] = sa;
    }
    __builtin_amdgcn_s_setprio(0);
    if (kb0 + 64 > kend){
      #pragma unroll
      for (int sub = 0; sub < 4; ++sub)
        #pragma unroll
        for (int r = 0; r < 4; ++r)
          if (kb0 + sub * 16 + cc * 4 + r >= kend) sc[sub][r] = -1e30f;
    }
    float m01 = fmaxf(fmaxf(sc[0][0], sc[0][1]), fmaxf(sc[0][2], sc[0][3]));
    float m23 = fmaxf(fmaxf(sc[1][0], sc[1][1]), fmaxf(sc[1][2], sc[1][3]));
    float m45 = fmaxf(fmaxf(sc[2][0], sc[2][1]), fmaxf(sc[2][2], sc[2][3]));
    float m67 = fmaxf(fmaxf(sc[3][0], sc[3][1]), fmaxf(sc[3][2], sc[3][3]));
    float pmax = fmaxf(fmaxf(m01, m23), fmaxf(m45, m67));
    pmax = fmaxf(pmax, __shfl_xor(pmax, 16));
    pmax = fmaxf(pmax, __shfl_xor(pmax, 32));
    if (!__all(pmax <= mrun + 11.54f)){
      float mnew = fmaxf(mrun, pmax);
      float alpha = exp2f(mrun - mnew);
      mrun = mnew;
      float alr[4];
      #pragma unroll
      for (int r = 0; r < 4; ++r) alr[r] = __shfl(alpha, cc * 4 + r);
      #pragma unroll
      for (int f = 0; f < 8; ++f)
        #pragma unroll
        for (int r = 0; r < 4; ++r) oacc[f][r] *= alr[r];
      lrun *= alpha;
    }
    float csum = 0.f;
    #pragma unroll
    for (int sub = 0; sub < 4; ++sub){
      float s0 = 0.f, s1 = 0.f;
      #pragma unroll
      for (int r = 0; r < 4; r += 2){
        float p0 = exp2f(sc[sub][r] - mrun);
        float p1 = exp2f(sc[sub][r + 1] - mrun);
        sc[sub][r] = p0; sc[sub][r + 1] = p1;
        s0 += p0; s1 += p1;
      }
      csum += s0 + s1;
    }
    csum += __shfl_xor(csum, 16);
    csum += __shfl_xor(csum, 32);
    lrun += csum;
    #pragma unroll
    for (int sub = 0; sub < 4; ++sub){
      uint2 w2;
      w2.x = cvtpk(sc[sub][0], sc[sub][1]);
      w2.y = cvtpk(sc[sub][2], sc[sub][3]);
      int gI = sub * 2 + (cc >> 1);
      *(uint2*)(Pb + qq * 128 + ((gI ^ (qq & 7)) * 16) + (cc & 1) * 8) = w2;
    }
    v8s pf0 = *(const v8s*)(Pb + qq * 128 + (((cc) ^ (qq & 7)) * 16));
    v8s pf1 = *(const v8s*)(Pb + qq * 128 + (((4 + cc) ^ (qq & 7)) * 16));
    __builtin_amdgcn_s_setprio(1);
    #pragma unroll
    for (int hdb = 0; hdb < 8; ++hdb){
      int row = hdb * 16 + qq;
      v8s vf0 = *(const v8s*)(Vb + row * 128 + (((cc) ^ (row & 7)) * 16));
      v8s vf1 = *(const v8s*)(Vb + row * 128 + (((4 + cc) ^ (row & 7)) * 16));
      oacc[hdb] = __builtin_amdgcn_mfma_f32_16x16x32_bf16(pf0, vf0, oacc[hdb], 0, 0, 0);
      oacc[hdb] = __builtin_amdgcn_mfma_f32_16x16x32_bf16(pf1, vf1, oacc[hdb], 0, 0, 0);
    }
    __builtin_amdgcn_s_setprio(0);
    __syncthreads();
  }

  if (mlbuf){
    float* op = z ? op1 : op0;
    #pragma unroll
    for (int hdb = 0; hdb < 8; ++hdb)
      #pragma unroll
      for (int r = 0; r < 4; ++r){
        int qrow = q0 + cc * 4 + r;
        if (qrow < Sq)
          op[(size_t)qrow * DMODEL + h * HDIM + hdb * 16 + qq] = oacc[hdb][r];
      }
    if (cc == 0 && q0 + qq < Sq)
      mlbuf[(size_t)z * NH * Sq + (size_t)h * Sq + q0 + qq] = make_float2(mrun, lrun);
  } else {
    float linv = 1.f / lrun;
    float lr[4];
    #pragma unroll
    for (int r = 0; r < 4; ++r) lr[r] = __shfl(linv, cc * 4 + r);
    #pragma unroll
    for (int hdb = 0; hdb < 8; ++hdb)
      #pragma unroll
      for (int r = 0; r < 4; ++r){
        int qrow = q0 + cc * 4 + r;
        if (qrow < Sq)
          O[(size_t)qrow * DMODEL + h * HDIM + hdb * 16 + qq] = f2b(oacc[hdb][r] * lr[r]);
      }
  }
}

// ---------------- host launch ----------------
extern "C" void kernel_launch(void* const* d_in, const int* in_sizes, int n_in,
                              void* d_out, int out_size, void* d_ws, size_t ws_size,
                              hipStream_t stream){
  (void)in_sizes; (void)n_in; (void)out_size; (void)ws_size;
  const float* x     = (const float*)d_in[0];
  const float* ctx   = (const float*)d_in[1];
  const float* t_mod = (const float*)d_in[2];
  const float* ropec = (const float*)d_in[3];
  const float* ropes = (const float*)d_in[4];
  const float* modu  = (const float*)d_in[5];
  const float* sa_qw = (const float*)d_in[6];  const float* sa_qb = (const float*)d_in[7];
  const float* sa_kw = (const float*)d_in[8];  const float* sa_kb = (const float*)d_in[9];
  const float* sa_vw = (const float*)d_in[10]; const float* sa_vb = (const float*)d_in[11];
  const float* sa_ow = (const float*)d_in[12]; const float* sa_ob = (const float*)d_in[13];
  const float* sa_nq = (const float*)d_in[14]; const float* sa_nk = (const float*)d_in[15];
  const float* ca_qw = (const float*)d_in[16]; const float* ca_qb = (const float*)d_in[17];
  const float* ca_kw = (const float*)d_in[18]; const float* ca_kb = (const float*)d_in[19];
  const float* ca_vw = (const float*)d_in[20]; const float* ca_vb = (const float*)d_in[21];
  const float* ca_ow = (const float*)d_in[22]; const float* ca_ob = (const float*)d_in[23];
  const float* ca_nq = (const float*)d_in[24]; const float* ca_nk = (const float*)d_in[25];
  const float* n3w   = (const float*)d_in[26]; const float* n3b   = (const float*)d_in[27];
  const float* fw1   = (const float*)d_in[28]; const float* fb1   = (const float*)d_in[29];
  const float* fw2   = (const float*)d_in[30]; const float* fb2   = (const float*)d_in[31];
  float* out = (float*)d_out;

  const float QSCALE = 0.08838834764831845f * 1.4426950408889634f;

  char* wsp = (char*)d_ws;
  size_t off = 0;
  auto alloc = [&](size_t b){ void* p = wsp + off; off += (b + 255) & ~(size_t)255; return p; };
  const size_t WW = (size_t)DMODEL * DMODEL * 2;
  float* modc = (float*)alloc(6 * DMODEL * 4);
  u16b* w1T   = (u16b*)alloc((size_t)FFND * DMODEL * 2);
  u16b* w2T   = (u16b*)alloc((size_t)DMODEL * FFND * 2);
  u16b* h_bf  = (u16b*)alloc((size_t)S_LEN * DMODEL * 2);
  float* pre0 = (float*)alloc((size_t)S_LEN * DMODEL * 4);
  size_t region0 = off;
  u16b* sa_qkvT = (u16b*)alloc(3 * WW);
  u16b* sa_owT  = (u16b*)alloc(WW);
  u16b* ca_qwT  = (u16b*)alloc(WW);
  u16b* ca_kvT  = (u16b*)alloc(2 * WW);
  u16b* ca_owT  = (u16b*)alloc(WW);
  float* x2    = (float*)alloc((size_t)S_LEN * DMODEL * 4);
  float* pre2  = (float*)alloc((size_t)LCTX * DMODEL * 4);
  u16b* qb     = (u16b*)alloc((size_t)S_LEN * DMODEL * 2);   // qb..kb = 22.1MB f32-partial span
  u16b* kb     = (u16b*)alloc((size_t)S_LEN * DMODEL * 2);
  u16b* vb     = (u16b*)alloc((size_t)S_LEN * DMODEL * 2);   // vb..ab = 22.1MB f32-partial span
  u16b* ab     = (u16b*)alloc((size_t)S_LEN * DMODEL * 2);
  u16b* ctxb   = (u16b*)alloc((size_t)LCTX * DMODEL * 2);
  u16b* k2b    = (u16b*)alloc((size_t)LCTX * DMODEL * 2);
  u16b* v2b    = (u16b*)alloc((size_t)LCTX * DMODEL * 2);
  u16b* vts    = (u16b*)alloc((size_t)NH * HDIM * SPAD_SELF * 2);
  u16b* vtc    = (u16b*)alloc((size_t)NH * HDIM * LCTX * 2);
  u16b* fmid = (u16b*)(wsp + region0);
  float* fpart = (float*)(wsp + region0 + (size_t)S_LEN * FFND * 2);

  add_vec<<<36, 256, 0, stream>>>(modu, t_mod, modc, 6 * DMODEL);

  WJobs jobs; int t = 0;
  auto addjob = [&](int i, const float* w_, u16b* wt, int K, int N){
    jobs.j[i].W = w_; jobs.j[i].WT = wt; jobs.j[i].K = K; jobs.j[i].N = N; jobs.j[i].t0 = t;
    t += (K / 32) * (N / 32);
  };
  addjob(0, sa_qw, sa_qkvT, DMODEL, DMODEL);
  addjob(1, sa_kw, sa_qkvT + (size_t)DMODEL * DMODEL, DMODEL, DMODEL);
  addjob(2, sa_vw, sa_qkvT + (size_t)2 * DMODEL * DMODEL, DMODEL, DMODEL);
  addjob(3, sa_ow, sa_owT, DMODEL, DMODEL);
  addjob(4, ca_qw, ca_qwT, DMODEL, DMODEL);
  addjob(5, ca_kw, ca_kvT, DMODEL, DMODEL);
  addjob(6, ca_vw, ca_kvT + (size_t)DMODEL * DMODEL, DMODEL, DMODEL);
  addjob(7, ca_ow, ca_owT, DMODEL, DMODEL);
  addjob(8, fw1, w1T, DMODEL, FFND);
  addjob(9, fw2, w2T, FFND, DMODEL);
  wconv<<<t, 256, 0, stream>>>(jobs);

  f2b_kernel<<<(LCTX * DMODEL) / 256, 256, 0, stream>>>(ctx, ctxb, LCTX * DMODEL);

  const int RED_G = (S_LEN * DMODEL / 4 + 255) / 256;

  // ---- self attention branch ----
  ln_mod<<<S_LEN, 256, 0, stream>>>(x, modc + DMODEL, modc, 1.f, h_bf);
  {
    Segs sg;
    sg.s[0] = { sa_qb, pre0, nullptr };
    sg.s[1] = { sa_kb, x2,   nullptr };
    sg.s[2] = { sa_vb, nullptr, vb   };
    gemm_seg<<<dim3(29, 36), 256, 0, stream>>>(h_bf, sa_qkvT, sg, S_LEN, 3 * DMODEL, DMODEL);
  }
  rms_rope<<<S_LEN, 256, 0, stream>>>(pre0, sa_nq, ropec, ropes, QSCALE, qb);
  rms_rope<<<S_LEN, 256, 0, stream>>>(x2, sa_nk, ropec, ropes, 1.f, kb);
  vtrans<<<dim3(SPAD_SELF / 32, 12), 256, 0, stream>>>(vb, vts, S_LEN, SPAD_SELF);
  flash_attn<<<dim3(29, 12, 2), 512, 0, stream>>>(qb, kb, vts, ab,
      (float*)pre0, (float*)x2, (float2*)vb, S_LEN, S_LEN, 1856, SPAD_SELF);
  merge_o<<<RED_G, 256, 0, stream>>>(
      (const float*)pre0, (const float*)x2, (const float2*)vb, ab, S_LEN);
  // sa o-proj split-K x2: partials -> pre0 (dead) and qb..kb span (dead)
  gemm_bt<6><<<dim3(29, 12, 2), 256, 0, stream>>>(ab, sa_owT, nullptr,
      (float*)pre0, (float*)qb, nullptr, S_LEN, DMODEL, DMODEL, 768);
  // fused: x2 = x + g_msa*(o + sa_ob); h_bf = LN(x2)*n3w + n3b
  red2_ln<<<S_LEN, 256, 0, stream>>>((const float*)pre0, (const float*)qb,
      x, modc + 2 * DMODEL, sa_ob, n3w, n3b, 0.f, x2, h_bf);

  // ---- cross attention branch ----
  // ca_q split-K x2: partials -> qb..kb (dead) and vb..ab (dead)
  gemm_bt<6><<<dim3(29, 12, 2), 256, 0, stream>>>(h_bf, ca_qwT, nullptr,
      (float*)qb, (float*)vb, nullptr, S_LEN, DMODEL, DMODEL, 768);
  red2<<<RED_G, 256, 0, stream>>>((const float*)qb, (const float*)vb,
      nullptr, nullptr, ca_qb, pre0, S_LEN * DMODEL);
  {
    Segs sg;
    sg.s[0] = { ca_kb, pre2, nullptr };
    sg.s[1] = { ca_vb, nullptr, v2b  };
    sg.s[2] = { ca_vb, nullptr, v2b  };
    gemm_seg<<<dim3(4, 24), 256, 0, stream>>>(ctxb, ca_kvT, sg, LCTX, 2 * DMODEL, DMODEL);
  }
  rms_rope<<<S_LEN, 256, 0, stream>>>(pre0, ca_nq, nullptr, nullptr, QSCALE, qb);
  rms_rope<<<LCTX, 256, 0, stream>>>(pre2, ca_nk, nullptr, nullptr, 1.f, k2b);
  vtrans<<<dim3(16, 12), 256, 0, stream>>>(v2b, vtc, LCTX, LCTX);
  flash_attn<<<dim3(29, 12, 2), 512, 0, stream>>>(qb, k2b, vtc, ab,
      (float*)pre0, (float*)kb, (float2*)vts, S_LEN, LCTX, 256, LCTX);
  merge_o<<<RED_G, 256, 0, stream>>>(
      (const float*)pre0, (const float*)kb, (const float2*)vts, ab, S_LEN);
  // ca o-proj split-K x2: partials -> qb..kb (dead) and sa_qkvT region (dead)
  gemm_bt<6><<<dim3(29, 12, 2), 256, 0, stream>>>(ab, ca_owT, nullptr,
      (float*)qb, (float*)sa_qkvT, nullptr, S_LEN, DMODEL, DMODEL, 768);
  // fused: pre0 = x2 + (o + ca_ob); h_bf = LN(pre0)*(1+sc_mlp) + sh_mlp
  red2_ln<<<S_LEN, 256, 0, stream>>>((const float*)qb, (const float*)sa_qkvT,
      x2, nullptr, ca_ob, modc + 4 * DMODEL, modc + 3 * DMODEL, 1.f, pre0, h_bf);

  // ---- FFN ----
  gemm_bt<3><<<dim3(29, 70), 256, 0, stream>>>(h_bf, w1T, fb1,
      nullptr, nullptr, fmid, S_LEN, FFND, DMODEL, DMODEL);
  gemm_bt<5><<<dim3(29, 12, 2), 256, 0, stream>>>(fmid, w2T, nullptr,
      fpart, nullptr, nullptr, S_LEN, DMODEL, FFND, FFND / 2);
  red2<<<RED_G, 256, 0, stream>>>(fpart, fpart + (size_t)S_LEN * DMODEL,
      pre0, modc + 5 * DMODEL, fb2, out, S_LEN * DMODEL);
}

// Round 12
// 930.409 us; speedup vs baseline: 1.2943x; 1.2943x over previous
//
#include <hip/hip_runtime.h>
#include <cstdint>

#define S_LEN 3600
#define DMODEL 1536
#define LCTX 512
#define NH 12
#define HDIM 128
#define FFND 8960
#define SPAD_SELF 3648

typedef short v8s __attribute__((ext_vector_type(8)));
typedef float v4f __attribute__((ext_vector_type(4)));
typedef unsigned short u16b;
typedef unsigned int u32b;

#define AS1 __attribute__((address_space(1)))
#define AS3 __attribute__((address_space(3)))

__device__ __forceinline__ void gl_lds16(const void* g, void* l){
  __builtin_amdgcn_global_load_lds((AS1 const void*)g, (AS3 void*)l, 16, 0, 0);
}

__device__ __forceinline__ u16b f2b(float f){
  union { float f; u32b i; } x; x.f = f;
  u32b r = x.i + 0x7fffu + ((x.i >> 16) & 1u);
  return (u16b)(r >> 16);
}

__device__ __forceinline__ u32b cvtpk(float a, float b){
  u32b r;
  asm("v_cvt_pk_bf16_f32 %0, %1, %2" : "=v"(r) : "v"(a), "v"(b));
  return r;
}

__device__ __forceinline__ int swz4(int row){ return (row ^ (row >> 2)) & 3; }

// bijective XCD swizzle (m204)
__device__ __forceinline__ int xcd_swz(int orig, int nwg){
  int q8 = nwg >> 3, r8 = nwg & 7;
  int xcd = orig & 7, idx = orig >> 3;
  return (xcd < r8 ? xcd * (q8 + 1) : r8 * (q8 + 1) + (xcd - r8) * q8) + idx;
}

// ---------------- small elementwise kernels ----------------
__global__ void add_vec(const float* __restrict__ a, const float* __restrict__ b,
                        float* __restrict__ o, int n){
  int i = blockIdx.x * 256 + threadIdx.x;
  if (i < n) o[i] = a[i] + b[i];
}

__global__ void f2b_kernel(const float* __restrict__ in, u16b* __restrict__ out, int n){
  int i = blockIdx.x * 256 + threadIdx.x;
  if (i < n) out[i] = f2b(in[i]);
}

// ---------------- fused transpose-convert of all weights ----------------
struct WJob { const float* W; u16b* WT; int K; int N; int t0; };
struct WJobs { WJob j[10]; };

__global__ __launch_bounds__(256) void wconv(WJobs jobs){
  __shared__ float tile[32][33];
  int b = blockIdx.x;
  int ji = 0;
  #pragma unroll
  for (int i = 0; i < 10; ++i) if (b >= jobs.j[i].t0) ji = i;
  WJob jb = jobs.j[ji];
  int rel = b - jb.t0;
  int ntn = jb.N / 32;
  int k0 = (rel / ntn) * 32, n0 = (rel % ntn) * 32;
  int tx = threadIdx.x & 31, ty = threadIdx.x >> 5;
  #pragma unroll
  for (int r = ty; r < 32; r += 8) tile[r][tx] = jb.W[(size_t)(k0 + r) * jb.N + n0 + tx];
  __syncthreads();
  #pragma unroll
  for (int r = ty; r < 32; r += 8) jb.WT[(size_t)(n0 + r) * jb.K + k0 + tx] = f2b(tile[tx][r]);
}

// ---------------- per-head V transpose ----------------
__global__ __launch_bounds__(256) void vtrans(const u16b* __restrict__ V,
                                              u16b* __restrict__ Vt,
                                              int S, int Spad){
  __shared__ u16b t[32][136];
  int h = blockIdx.y, kb = blockIdx.x * 32, tid = threadIdx.x;
  int row = tid >> 3, ch = tid & 7;
  int key = kb + row;
  if (key < S){
    float4 a = *(const float4*)(V + (size_t)key * DMODEL + h * HDIM + ch * 16);
    float4 b = *(const float4*)(V + (size_t)key * DMODEL + h * HDIM + ch * 16 + 8);
    *(float4*)&t[row][ch * 16] = a;
    *(float4*)&t[row][ch * 16 + 8] = b;
  } else {
    float4 z = {0.f, 0.f, 0.f, 0.f};
    *(float4*)&t[row][ch * 16] = z;
    *(float4*)&t[row][ch * 16 + 8] = z;
  }
  __syncthreads();
  int hd = tid >> 1, kc = (tid & 1) * 16;
  u16b* dst = Vt + ((size_t)h * HDIM + hd) * Spad + kb + kc;
  #pragma unroll
  for (int e = 0; e < 16; e += 2){
    u32b pk = ((u32b)t[kc + e][hd]) | (((u32b)t[kc + e + 1][hd]) << 16);
    *(u32b*)(dst + e) = pk;
  }
}

// ---------------- LayerNorm (mod) -> bf16 ----------------
__global__ __launch_bounds__(256) void ln_mod(const float* __restrict__ X,
                                              const float* __restrict__ gamma,
                                              const float* __restrict__ beta,
                                              float gadd, u16b* __restrict__ out){
  int row = blockIdx.x;
  const float* xr = X + (size_t)row * DMODEL;
  int tid = threadIdx.x;
  float v[6]; float s1 = 0.f, s2 = 0.f;
  #pragma unroll
  for (int j = 0; j < 6; ++j){ v[j] = xr[tid + j * 256]; s1 += v[j]; s2 += v[j] * v[j]; }
  #pragma unroll
  for (int o = 1; o < 64; o <<= 1){ s1 += __shfl_xor(s1, o); s2 += __shfl_xor(s2, o); }
  __shared__ float red[8];
  int wid = tid >> 6, lane = tid & 63;
  if (!lane){ red[wid * 2] = s1; red[wid * 2 + 1] = s2; }
  __syncthreads();
  s1 = red[0] + red[2] + red[4] + red[6];
  s2 = red[1] + red[3] + red[5] + red[7];
  float mu = s1 / DMODEL;
  float var = s2 / DMODEL - mu * mu;
  float rstd = rsqrtf(var + 1e-6f);
  #pragma unroll
  for (int j = 0; j < 6; ++j){
    int c = tid + j * 256;
    out[(size_t)row * DMODEL + c] = f2b((v[j] - mu) * rstd * (gamma[c] + gadd) + beta[c]);
  }
}

// ---------------- fused: y = res + gate*(p0+p1+bias); h = LN(y)*gamma(+gadd)+beta ----------------
__global__ __launch_bounds__(256) void red2_ln(
    const float* __restrict__ p0, const float* __restrict__ p1,
    const float* __restrict__ res, const float* __restrict__ gate,
    const float* __restrict__ bias,
    const float* __restrict__ gamma, const float* __restrict__ beta, float gadd,
    float* __restrict__ yOut, u16b* __restrict__ hOut)
{
  int row = blockIdx.x, tid = threadIdx.x;
  size_t base = (size_t)row * DMODEL;
  float y[6]; float s1 = 0.f, s2 = 0.f;
  #pragma unroll
  for (int j = 0; j < 6; ++j){
    int c = tid + j * 256;
    float v = p0[base + c] + p1[base + c] + bias[c];
    if (gate) v *= gate[c];
    v += res[base + c];
    y[j] = v; s1 += v; s2 += v * v;
  }
  #pragma unroll
  for (int o = 1; o < 64; o <<= 1){ s1 += __shfl_xor(s1, o); s2 += __shfl_xor(s2, o); }
  __shared__ float red[8];
  int wid = tid >> 6, lane = tid & 63;
  if (!lane){ red[wid * 2] = s1; red[wid * 2 + 1] = s2; }
  __syncthreads();
  s1 = red[0] + red[2] + red[4] + red[6];
  s2 = red[1] + red[3] + red[5] + red[7];
  float mu = s1 / DMODEL;
  float var = s2 / DMODEL - mu * mu;
  float rstd = rsqrtf(var + 1e-6f);
  #pragma unroll
  for (int j = 0; j < 6; ++j){
    int c = tid + j * 256;
    yOut[base + c] = y[j];
    hOut[base + c] = f2b((y[j] - mu) * rstd * (gamma[c] + gadd) + beta[c]);
  }
}

// ---------------- RMSNorm (+optional RoPE) fp32 -> bf16 ----------------
__global__ __launch_bounds__(256) void rms_rope(const float* __restrict__ X,
                                                const float* __restrict__ w,
                                                const float* __restrict__ cosT,
                                                const float* __restrict__ sinT,
                                                float qmul,
                                                u16b* __restrict__ out){
  int row = blockIdx.x;
  const float* xr = X + (size_t)row * DMODEL;
  int tid = threadIdx.x;
  float2 v[3]; float ss = 0.f;
  #pragma unroll
  for (int j = 0; j < 3; ++j){
    v[j] = *(const float2*)(xr + 2 * (tid + j * 256));
    ss += v[j].x * v[j].x + v[j].y * v[j].y;
  }
  #pragma unroll
  for (int o = 1; o < 64; o <<= 1) ss += __shfl_xor(ss, o);
  __shared__ float red[4];
  int wid = tid >> 6, lane = tid & 63;
  if (!lane) red[wid] = ss;
  __syncthreads();
  ss = red[0] + red[1] + red[2] + red[3];
  float rstd = rsqrtf(ss / DMODEL + 1e-6f);
  #pragma unroll
  for (int j = 0; j < 3; ++j){
    int p = tid + j * 256;
    float xe = v[j].x * rstd * w[2 * p];
    float xo = v[j].y * rstd * w[2 * p + 1];
    float oe, oo;
    if (cosT){
      int d = p & 63;
      float c = cosT[row * 64 + d], sn = sinT[row * 64 + d];
      oe = xe * c - xo * sn; oo = xe * sn + xo * c;
    } else { oe = xe; oo = xo; }
    oe *= qmul; oo *= qmul;
    u32b packed = ((u32b)f2b(oe)) | (((u32b)f2b(oo)) << 16);
    *(u32b*)(out + (size_t)row * DMODEL + 2 * p) = packed;
  }
}

// ---------------- segment descriptors ----------------
struct Seg { const float* bias; float* outF; u16b* outB; };
struct Segs { Seg s[3]; };

// ---------------- 128x128 GEMM, 3-buffer counted-vmcnt pipeline ----------------
// EPI: 3 = gelu->bf16 (bias); 5 = split-K partial contiguous (outF + z*M*N);
//      6 = split-K partial two-pointer (z ? outF2 : outF)
template<int EPI>
__global__ __launch_bounds__(256, 2) void gemm_bt(
    const u16b* __restrict__ A, const u16b* __restrict__ BT,
    const float* __restrict__ bias, float* __restrict__ outF,
    float* __restrict__ outF2, u16b* __restrict__ outB,
    int M, int N, int K, int kLen)
{
  __shared__ char Ls[3][16384];
  const int tid = threadIdx.x, lane = tid & 63, wid = tid >> 6;
  const int nwg = gridDim.x * gridDim.y;
  const int swz = xcd_swz(blockIdx.x + gridDim.x * blockIdx.y, nwg);
  const int bm = (swz % gridDim.x) * 128, bn = (swz / gridDim.x) * 128;
  const int kbase = blockIdx.z * kLen;
  const int wm = (wid >> 1) * 64, wn = (wid & 1) * 64;
  v4f acc[4][4] = {};

  const u16b* pA[2]; const u16b* pB[2];
  #pragma unroll
  for (int c = 0; c < 2; ++c){
    int row = c * 64 + (tid >> 2);
    int col = (tid & 3) ^ swz4(row);
    pA[c] = A + (size_t)min(bm + row, M - 1) * K + kbase + col * 8;
    pB[c] = BT + (size_t)(bn + row) * K + kbase + col * 8;
  }
  auto stage = [&](int b){
    char* Lb = Ls[b];
    #pragma unroll
    for (int c = 0; c < 2; ++c){
      gl_lds16(pA[c], Lb + (c * 256 + tid) * 16);
      gl_lds16(pB[c], Lb + 8192 + (c * 256 + tid) * 16);
      pA[c] += 32; pB[c] += 32;
    }
  };

  const int chk = lane >> 4, qr = lane & 15;
  int offA[4], offB[4];
  #pragma unroll
  for (int f = 0; f < 4; ++f){
    int ra = wm + f * 16 + qr;
    offA[f] = ra * 64 + ((chk ^ swz4(ra)) * 16);
    int rb = wn + f * 16 + qr;
    offB[f] = 8192 + rb * 64 + ((chk ^ swz4(rb)) * 16);
  }

  const int nt = kLen / 32;
  stage(0); stage(1);
  int s = 0, sp = 2;
  for (int t = 0; t < nt; ++t){
    if (t + 1 < nt) asm volatile("s_waitcnt vmcnt(4)" ::: "memory");
    else            asm volatile("s_waitcnt vmcnt(0)" ::: "memory");
    __builtin_amdgcn_s_barrier();
    if (t + 2 < nt) stage(sp);
    char* Lb = Ls[s];
    v8s af[4], bfr[4];
    #pragma unroll
    for (int f = 0; f < 4; ++f){
      af[f] = *(const v8s*)(Lb + offA[f]);
      bfr[f] = *(const v8s*)(Lb + offB[f]);
    }
    __builtin_amdgcn_s_setprio(1);
    #pragma unroll
    for (int i = 0; i < 4; ++i)
      #pragma unroll
      for (int j = 0; j < 4; ++j)
        acc[i][j] = __builtin_amdgcn_mfma_f32_16x16x32_bf16(af[i], bfr[j], acc[i][j], 0, 0, 0);
    __builtin_amdgcn_s_setprio(0);
    s = (s == 2) ? 0 : s + 1;
    sp = (sp == 2) ? 0 : sp + 1;
  }
  const int rr = lane >> 4;
  float* op6 = (EPI == 6) ? (blockIdx.z ? outF2 : outF) : outF;
  #pragma unroll
  for (int i = 0; i < 4; ++i){
    #pragma unroll
    for (int j = 0; j < 4; ++j){
      int n = bn + wn + j * 16 + qr;
      float bv = (EPI == 3) ? bias[n] : 0.f;
      #pragma unroll
      for (int r = 0; r < 4; ++r){
        int m = bm + wm + i * 16 + rr * 4 + r;
        if (m < M){
          float val = acc[i][j][r] + bv;
          size_t idx = (size_t)m * N + n;
          if (EPI == 3){
            float t3 = val * val * val;
            float g = val / (1.f + __expf(-1.5957691216057308f * (val + 0.044715f * t3)));
            outB[idx] = f2b(g);
          } else if (EPI == 5){
            outF[(size_t)blockIdx.z * M * N + idx] = val;
          } else {
            op6[idx] = val;
          }
        }
      }
    }
  }
}

// ---------------- segmented 128^2 GEMM (QKV / ca K/V fused) ----------------
__global__ __launch_bounds__(256, 2) void gemm_seg(
    const u16b* __restrict__ A, const u16b* __restrict__ BT,
    Segs segs, int M, int N, int K)
{
  __shared__ char Ls[3][16384];
  const int tid = threadIdx.x, lane = tid & 63, wid = tid >> 6;
  const int nwg = gridDim.x * gridDim.y;
  const int swz = xcd_swz(blockIdx.x + gridDim.x * blockIdx.y, nwg);
  const int bm = (swz % gridDim.x) * 128, bn = (swz / gridDim.x) * 128;
  const int wm = (wid >> 1) * 64, wn = (wid & 1) * 64;
  v4f acc[4][4] = {};

  const u16b* pA[2]; const u16b* pB[2];
  #pragma unroll
  for (int c = 0; c < 2; ++c){
    int row = c * 64 + (tid >> 2);
    int col = (tid & 3) ^ swz4(row);
    pA[c] = A + (size_t)min(bm + row, M - 1) * K + col * 8;
    pB[c] = BT + (size_t)(bn + row) * K + col * 8;
  }
  auto stage = [&](int b){
    char* Lb = Ls[b];
    #pragma unroll
    for (int c = 0; c < 2; ++c){
      gl_lds16(pA[c], Lb + (c * 256 + tid) * 16);
      gl_lds16(pB[c], Lb + 8192 + (c * 256 + tid) * 16);
      pA[c] += 32; pB[c] += 32;
    }
  };

  const int chk = lane >> 4, qr = lane & 15;
  int offA[4], offB[4];
  #pragma unroll
  for (int f = 0; f < 4; ++f){
    int ra = wm + f * 16 + qr;
    offA[f] = ra * 64 + ((chk ^ swz4(ra)) * 16);
    int rb = wn + f * 16 + qr;
    offB[f] = 8192 + rb * 64 + ((chk ^ swz4(rb)) * 16);
  }

  const int nt = K / 32;
  stage(0); stage(1);
  int s = 0, sp = 2;
  for (int t = 0; t < nt; ++t){
    if (t + 1 < nt) asm volatile("s_waitcnt vmcnt(4)" ::: "memory");
    else            asm volatile("s_waitcnt vmcnt(0)" ::: "memory");
    __builtin_amdgcn_s_barrier();
    if (t + 2 < nt) stage(sp);
    char* Lb = Ls[s];
    v8s af[4], bfr[4];
    #pragma unroll
    for (int f = 0; f < 4; ++f){
      af[f] = *(const v8s*)(Lb + offA[f]);
      bfr[f] = *(const v8s*)(Lb + offB[f]);
    }
    __builtin_amdgcn_s_setprio(1);
    #pragma unroll
    for (int i = 0; i < 4; ++i)
      #pragma unroll
      for (int j = 0; j < 4; ++j)
        acc[i][j] = __builtin_amdgcn_mfma_f32_16x16x32_bf16(af[i], bfr[j], acc[i][j], 0, 0, 0);
    __builtin_amdgcn_s_setprio(0);
    s = (s == 2) ? 0 : s + 1;
    sp = (sp == 2) ? 0 : sp + 1;
  }
  const int seg = bn / 1536;
  const Seg sg = segs.s[seg];
  const int rr = lane >> 4;
  #pragma unroll
  for (int i = 0; i < 4; ++i){
    #pragma unroll
    for (int j = 0; j < 4; ++j){
      int nloc = bn - seg * 1536 + wn + j * 16 + qr;
      float bv = sg.bias[nloc];
      #pragma unroll
      for (int r = 0; r < 4; ++r){
        int m = bm + wm + i * 16 + rr * 4 + r;
        if (m < M){
          float val = acc[i][j][r] + bv;
          size_t idx = (size_t)m * 1536 + nloc;
          if (sg.outB) sg.outB[idx] = f2b(val);
          else sg.outF[idx] = val;
        }
      }
    }
  }
}

// ---------------- split-K x2 reduce: out = res? + gate? * (p0+p1+bias) ----------------
__global__ __launch_bounds__(256) void red2(const float* __restrict__ p0,
                                            const float* __restrict__ p1,
                                            const float* __restrict__ res,
                                            const float* __restrict__ gate,
                                            const float* __restrict__ bias,
                                            float* __restrict__ out, int total){
  int i4 = blockIdx.x * 256 + threadIdx.x;
  if (i4 * 4 >= total) return;
  int base = i4 * 4, n = base % DMODEL;
  float4 a = *(const float4*)(p0 + base);
  float4 b = *(const float4*)(p1 + base);
  float4 bv = *(const float4*)(bias + n);
  float gx = 1.f, gy = 1.f, gz = 1.f, gw = 1.f;
  if (gate){ float4 g = *(const float4*)(gate + n); gx = g.x; gy = g.y; gz = g.z; gw = g.w; }
  float rx = 0.f, ry = 0.f, rz = 0.f, rw = 0.f;
  if (res){ float4 r = *(const float4*)(res + base); rx = r.x; ry = r.y; rz = r.z; rw = r.w; }
  float4 o;
  o.x = rx + gx * (a.x + b.x + bv.x);
  o.y = ry + gy * (a.y + b.y + bv.y);
  o.z = rz + gz * (a.z + b.z + bv.z);
  o.w = rw + gw * (a.w + b.w + bv.w);
  *(float4*)(out + base) = o;
}

// ---------------- split-flash merge ----------------
__global__ __launch_bounds__(256) void merge_o(const float* __restrict__ op0,
                                               const float* __restrict__ op1,
                                               const float2* __restrict__ ml,
                                               u16b* __restrict__ outO, int Sq){
  int i4 = blockIdx.x * 256 + threadIdx.x;
  const int perRow = DMODEL / 4;
  if (i4 >= Sq * perRow) return;
  int row = i4 / perRow, c4 = (i4 % perRow) * 4;
  int h = c4 >> 7;
  float2 ml0 = ml[h * Sq + row];
  float2 ml1 = ml[NH * Sq + h * Sq + row];
  float M = fmaxf(ml0.x, ml1.x);
  float w0 = exp2f(ml0.x - M), w1 = exp2f(ml1.x - M);
  float inv = 1.f / (ml0.y * w0 + ml1.y * w1);
  float4 a = *(const float4*)(op0 + (size_t)row * DMODEL + c4);
  float4 b = *(const float4*)(op1 + (size_t)row * DMODEL + c4);
  u32b lo = ((u32b)f2b((a.x * w0 + b.x * w1) * inv)) | (((u32b)f2b((a.y * w0 + b.y * w1) * inv)) << 16);
  u32b hi = ((u32b)f2b((a.z * w0 + b.z * w1) * inv)) | (((u32b)f2b((a.w * w0 + b.w * w1) * inv)) << 16);
  uint2 w2; w2.x = lo; w2.y = hi;
  *(uint2*)(outO + (size_t)row * DMODEL + c4) = w2;
}

// ---------------- flash attention: KVBLK=64, single KV buffer, key-split x2 ----------------
__global__ __launch_bounds__(256, 4) void flash_attn(
    const u16b* __restrict__ Q, const u16b* __restrict__ Kp,
    const u16b* __restrict__ Vt, u16b* __restrict__ O,
    float* __restrict__ op0, float* __restrict__ op1,
    float2* __restrict__ mlbuf,
    int Sq, int Sk, int ksplit, int Spad)
{
  __shared__ char KV[32768];
  __shared__ char Pall[8192];
  const int tid = threadIdx.x, lane = tid & 63, wid = tid >> 6;
  const int h = blockIdx.y;
  const int z = blockIdx.z;
  const int kbeg = z * ksplit;
  const int kend = min(kbeg + ksplit, Sk);
  const int q0 = blockIdx.x * 64 + wid * 16;
  const int qq = lane & 15, cc = lane >> 4;
  char* Kb = KV; char* Vb = KV + 16384;
  char* Pb = Pall + wid * 2048;

  v8s qf[4];
  {
    int qrow = min(q0 + qq, Sq - 1);
    const u16b* qp = Q + (size_t)qrow * DMODEL + h * HDIM + cc * 8;
    #pragma unroll
    for (int ks = 0; ks < 4; ++ks) qf[ks] = *(const v8s*)(qp + ks * 32);
  }

  auto stage = [&](int kb0){
    #pragma unroll
    for (int c = 0; c < 4; ++c){
      int seg = wid * 4 + c;
      int g = seg * 64 + lane;
      int krow = g >> 4, kcol = (g & 15) ^ (krow & 7);
      gl_lds16(Kp + (size_t)min(kb0 + krow, Sk - 1) * DMODEL + h * HDIM + kcol * 8,
               Kb + seg * 1024);
      int vrow = g >> 3, vcol = (g & 7) ^ (vrow & 7);
      gl_lds16(Vt + ((size_t)h * HDIM + vrow) * Spad + kb0 + vcol * 8,
               Vb + seg * 1024);
    }
  };

  float mrun = -1e30f, lrun = 0.f;
  v4f oacc[8] = {};
  const int nt = (kend - kbeg + 63) >> 6;

  for (int t = 0; t < nt; ++t){
    int kb0 = kbeg + (t << 6);
    stage(kb0);
    __syncthreads();
    v4f sc[4];
    __builtin_amdgcn_s_setprio(1);
    #pragma unroll
    for (int sub = 0; sub < 4; ++sub){
      v4f sa = {0.f, 0.f, 0.f, 0.f};
      int row = sub * 16 + qq;
      #pragma unroll
      for (int ks = 0; ks < 4; ++ks){
        v8s kf = *(const v8s*)(Kb + row * 256 + (((ks * 4 + cc) ^ (row & 7)) * 16));
        sa = __builtin_amdgcn_mfma_f32_16x16x32_bf16(kf, qf[ks], sa, 0, 0, 0);
      }
      sc[sub] = sa;
    }
    __builtin_amdgcn_s_setprio(0);
    if (kb0 + 64 > kend){
      #pragma unroll
      for (int sub = 0; sub < 4; ++sub)
        #pragma unroll
        for (int r = 0; r < 4; ++r)
          if (kb0 + sub * 16 + cc * 4 + r >= kend) sc[sub][r] = -1e30f;
    }
    float m01 = fmaxf(fmaxf(sc[0][0], sc[0][1]), fmaxf(sc[0][2], sc[0][3]));
    float m23 = fmaxf(fmaxf(sc[1][0], sc[1][1]), fmaxf(sc[1][2], sc[1][3]));
    float m45 = fmaxf(fmaxf(sc[2][0], sc[2][1]), fmaxf(sc[2][2], sc[2][3]));
    float m67 = fmaxf(fmaxf(sc[3][0], sc[3][1]), fmaxf(sc[3][2], sc[3][3]));
    float pmax = fmaxf(fmaxf(m01, m23), fmaxf(m45, m67));
    pmax = fmaxf(pmax, __shfl_xor(pmax, 16));
    pmax = fmaxf(pmax, __shfl_xor(pmax, 32));
    if (!__all(pmax <= mrun + 11.54f)){
      float mnew = fmaxf(mrun, pmax);
      float alpha = exp2f(mrun - mnew);
      mrun = mnew;
      float alr[4];
      #pragma unroll
      for (int r = 0; r < 4; ++r) alr[r] = __shfl(alpha, cc * 4 + r);
      #pragma unroll
      for (int f = 0; f < 8; ++f)
        #pragma unroll
        for (int r = 0; r < 4; ++r) oacc[f][r] *= alr[r];
      lrun *= alpha;
    }
    float csum = 0.f;
    #pragma unroll
    for (int sub = 0; sub < 4; ++sub){
      float s0 = 0.f, s1 = 0.f;
      #pragma unroll
      for (int r = 0; r < 4; r += 2){
        float p0 = exp2f(sc[sub][r] - mrun);
        float p1 = exp2f(sc[sub][r + 1] - mrun);
        sc[sub][r] = p0; sc[sub][r + 1] = p1;
        s0 += p0; s1 += p1;
      }
      csum += s0 + s1;
    }
    csum += __shfl_xor(csum, 16);
    csum += __shfl_xor(csum, 32);
    lrun += csum;
    #pragma unroll
    for (int sub = 0; sub < 4; ++sub){
      uint2 w2;
      w2.x = cvtpk(sc[sub][0], sc[sub][1]);
      w2.y = cvtpk(sc[sub][2], sc[sub][3]);
      int gI = sub * 2 + (cc >> 1);
      *(uint2*)(Pb + qq * 128 + ((gI ^ (qq & 7)) * 16) + (cc & 1) * 8) = w2;
    }
    v8s pf0 = *(const v8s*)(Pb + qq * 128 + (((cc) ^ (qq & 7)) * 16));
    v8s pf1 = *(const v8s*)(Pb + qq * 128 + (((4 + cc) ^ (qq & 7)) * 16));
    __builtin_amdgcn_s_setprio(1);
    #pragma unroll
    for (int hdb = 0; hdb < 8; ++hdb){
      int row = hdb * 16 + qq;
      v8s vf0 = *(const v8s*)(Vb + row * 128 + (((cc) ^ (row & 7)) * 16));
      v8s vf1 = *(const v8s*)(Vb + row * 128 + (((4 + cc) ^ (row & 7)) * 16));
      oacc[hdb] = __builtin_amdgcn_mfma_f32_16x16x32_bf16(pf0, vf0, oacc[hdb], 0, 0, 0);
      oacc[hdb] = __builtin_amdgcn_mfma_f32_16x16x32_bf16(pf1, vf1, oacc[hdb], 0, 0, 0);
    }
    __builtin_amdgcn_s_setprio(0);
    __syncthreads();
  }

  if (mlbuf){
    float* op = z ? op1 : op0;
    #pragma unroll
    for (int hdb = 0; hdb < 8; ++hdb)
      #pragma unroll
      for (int r = 0; r < 4; ++r){
        int qrow = q0 + cc * 4 + r;
        if (qrow < Sq)
          op[(size_t)qrow * DMODEL + h * HDIM + hdb * 16 + qq] = oacc[hdb][r];
      }
    if (cc == 0 && q0 + qq < Sq)
      mlbuf[(size_t)z * NH * Sq + (size_t)h * Sq + q0 + qq] = make_float2(mrun, lrun);
  } else {
    float linv = 1.f / lrun;
    float lr[4];
    #pragma unroll
    for (int r = 0; r < 4; ++r) lr[r] = __shfl(linv, cc * 4 + r);
    #pragma unroll
    for (int hdb = 0; hdb < 8; ++hdb)
      #pragma unroll
      for (int r = 0; r < 4; ++r){
        int qrow = q0 + cc * 4 + r;
        if (qrow < Sq)
          O[(size_t)qrow * DMODEL + h * HDIM + hdb * 16 + qq] = f2b(oacc[hdb][r] * lr[r]);
      }
  }
}

// ---------------- host launch ----------------
extern "C" void kernel_launch(void* const* d_in, const int* in_sizes, int n_in,
                              void* d_out, int out_size, void* d_ws, size_t ws_size,
                              hipStream_t stream){
  (void)in_sizes; (void)n_in; (void)out_size; (void)ws_size;
  const float* x     = (const float*)d_in[0];
  const float* ctx   = (const float*)d_in[1];
  const float* t_mod = (const float*)d_in[2];
  const float* ropec = (const float*)d_in[3];
  const float* ropes = (const float*)d_in[4];
  const float* modu  = (const float*)d_in[5];
  const float* sa_qw = (const float*)d_in[6];  const float* sa_qb = (const float*)d_in[7];
  const float* sa_kw = (const float*)d_in[8];  const float* sa_kb = (const float*)d_in[9];
  const float* sa_vw = (const float*)d_in[10]; const float* sa_vb = (const float*)d_in[11];
  const float* sa_ow = (const float*)d_in[12]; const float* sa_ob = (const float*)d_in[13];
  const float* sa_nq = (const float*)d_in[14]; const float* sa_nk = (const float*)d_in[15];
  const float* ca_qw = (const float*)d_in[16]; const float* ca_qb = (const float*)d_in[17];
  const float* ca_kw = (const float*)d_in[18]; const float* ca_kb = (const float*)d_in[19];
  const float* ca_vw = (const float*)d_in[20]; const float* ca_vb = (const float*)d_in[21];
  const float* ca_ow = (const float*)d_in[22]; const float* ca_ob = (const float*)d_in[23];
  const float* ca_nq = (const float*)d_in[24]; const float* ca_nk = (const float*)d_in[25];
  const float* n3w   = (const float*)d_in[26]; const float* n3b   = (const float*)d_in[27];
  const float* fw1   = (const float*)d_in[28]; const float* fb1   = (const float*)d_in[29];
  const float* fw2   = (const float*)d_in[30]; const float* fb2   = (const float*)d_in[31];
  float* out = (float*)d_out;

  const float QSCALE = 0.08838834764831845f * 1.4426950408889634f;

  char* wsp = (char*)d_ws;
  size_t off = 0;
  auto alloc = [&](size_t b){ void* p = wsp + off; off += (b + 255) & ~(size_t)255; return p; };
  const size_t WW = (size_t)DMODEL * DMODEL * 2;
  float* modc = (float*)alloc(6 * DMODEL * 4);
  u16b* w1T   = (u16b*)alloc((size_t)FFND * DMODEL * 2);
  u16b* w2T   = (u16b*)alloc((size_t)DMODEL * FFND * 2);
  u16b* h_bf  = (u16b*)alloc((size_t)S_LEN * DMODEL * 2);
  float* pre0 = (float*)alloc((size_t)S_LEN * DMODEL * 4);
  size_t region0 = off;
  u16b* sa_qkvT = (u16b*)alloc(3 * WW);
  u16b* sa_owT  = (u16b*)alloc(WW);
  u16b* ca_qwT  = (u16b*)alloc(WW);
  u16b* ca_kvT  = (u16b*)alloc(2 * WW);
  u16b* ca_owT  = (u16b*)alloc(WW);
  float* x2    = (float*)alloc((size_t)S_LEN * DMODEL * 4);
  float* pre2  = (float*)alloc((size_t)LCTX * DMODEL * 4);
  u16b* qb     = (u16b*)alloc((size_t)S_LEN * DMODEL * 2);   // qb..kb = 22.1MB f32-partial span
  u16b* kb     = (u16b*)alloc((size_t)S_LEN * DMODEL * 2);
  u16b* vb     = (u16b*)alloc((size_t)S_LEN * DMODEL * 2);   // vb..ab = 22.1MB f32-partial span
  u16b* ab     = (u16b*)alloc((size_t)S_LEN * DMODEL * 2);
  u16b* ctxb   = (u16b*)alloc((size_t)LCTX * DMODEL * 2);
  u16b* k2b    = (u16b*)alloc((size_t)LCTX * DMODEL * 2);
  u16b* v2b    = (u16b*)alloc((size_t)LCTX * DMODEL * 2);
  u16b* vts    = (u16b*)alloc((size_t)NH * HDIM * SPAD_SELF * 2);
  u16b* vtc    = (u16b*)alloc((size_t)NH * HDIM * LCTX * 2);
  u16b* fmid = (u16b*)(wsp + region0);
  float* fpart = (float*)(wsp + region0 + (size_t)S_LEN * FFND * 2);

  add_vec<<<36, 256, 0, stream>>>(modu, t_mod, modc, 6 * DMODEL);

  WJobs jobs; int t = 0;
  auto addjob = [&](int i, const float* w_, u16b* wt, int K, int N){
    jobs.j[i].W = w_; jobs.j[i].WT = wt; jobs.j[i].K = K; jobs.j[i].N = N; jobs.j[i].t0 = t;
    t += (K / 32) * (N / 32);
  };
  addjob(0, sa_qw, sa_qkvT, DMODEL, DMODEL);
  addjob(1, sa_kw, sa_qkvT + (size_t)DMODEL * DMODEL, DMODEL, DMODEL);
  addjob(2, sa_vw, sa_qkvT + (size_t)2 * DMODEL * DMODEL, DMODEL, DMODEL);
  addjob(3, sa_ow, sa_owT, DMODEL, DMODEL);
  addjob(4, ca_qw, ca_qwT, DMODEL, DMODEL);
  addjob(5, ca_kw, ca_kvT, DMODEL, DMODEL);
  addjob(6, ca_vw, ca_kvT + (size_t)DMODEL * DMODEL, DMODEL, DMODEL);
  addjob(7, ca_ow, ca_owT, DMODEL, DMODEL);
  addjob(8, fw1, w1T, DMODEL, FFND);
  addjob(9, fw2, w2T, FFND, DMODEL);
  wconv<<<t, 256, 0, stream>>>(jobs);

  f2b_kernel<<<(LCTX * DMODEL) / 256, 256, 0, stream>>>(ctx, ctxb, LCTX * DMODEL);

  const int RED_G = (S_LEN * DMODEL / 4 + 255) / 256;

  // ---- self attention branch ----
  ln_mod<<<S_LEN, 256, 0, stream>>>(x, modc + DMODEL, modc, 1.f, h_bf);
  {
    Segs sg;
    sg.s[0] = { sa_qb, pre0, nullptr };
    sg.s[1] = { sa_kb, x2,   nullptr };
    sg.s[2] = { sa_vb, nullptr, vb   };
    gemm_seg<<<dim3(29, 36), 256, 0, stream>>>(h_bf, sa_qkvT, sg, S_LEN, 3 * DMODEL, DMODEL);
  }
  rms_rope<<<S_LEN, 256, 0, stream>>>(pre0, sa_nq, ropec, ropes, QSCALE, qb);
  rms_rope<<<S_LEN, 256, 0, stream>>>(x2, sa_nk, ropec, ropes, 1.f, kb);
  vtrans<<<dim3(SPAD_SELF / 32, 12), 256, 0, stream>>>(vb, vts, S_LEN, SPAD_SELF);
  flash_attn<<<dim3(57, 12, 2), 256, 0, stream>>>(qb, kb, vts, ab,
      (float*)pre0, (float*)x2, (float2*)vb, S_LEN, S_LEN, 1856, SPAD_SELF);
  merge_o<<<RED_G, 256, 0, stream>>>(
      (const float*)pre0, (const float*)x2, (const float2*)vb, ab, S_LEN);
  // sa o-proj split-K x2: partials -> pre0 (dead) and qb..kb span (dead)
  gemm_bt<6><<<dim3(29, 12, 2), 256, 0, stream>>>(ab, sa_owT, nullptr,
      (float*)pre0, (float*)qb, nullptr, S_LEN, DMODEL, DMODEL, 768);
  // fused: x2 = x + g_msa*(o + sa_ob); h_bf = LN(x2)*n3w + n3b
  red2_ln<<<S_LEN, 256, 0, stream>>>((const float*)pre0, (const float*)qb,
      x, modc + 2 * DMODEL, sa_ob, n3w, n3b, 0.f, x2, h_bf);

  // ---- cross attention branch ----
  // ca_q split-K x2: partials -> qb..kb (dead) and vb..ab (dead)
  gemm_bt<6><<<dim3(29, 12, 2), 256, 0, stream>>>(h_bf, ca_qwT, nullptr,
      (float*)qb, (float*)vb, nullptr, S_LEN, DMODEL, DMODEL, 768);
  red2<<<RED_G, 256, 0, stream>>>((const float*)qb, (const float*)vb,
      nullptr, nullptr, ca_qb, pre0, S_LEN * DMODEL);
  {
    Segs sg;
    sg.s[0] = { ca_kb, pre2, nullptr };
    sg.s[1] = { ca_vb, nullptr, v2b  };
    sg.s[2] = { ca_vb, nullptr, v2b  };
    gemm_seg<<<dim3(4, 24), 256, 0, stream>>>(ctxb, ca_kvT, sg, LCTX, 2 * DMODEL, DMODEL);
  }
  rms_rope<<<S_LEN, 256, 0, stream>>>(pre0, ca_nq, nullptr, nullptr, QSCALE, qb);
  rms_rope<<<LCTX, 256, 0, stream>>>(pre2, ca_nk, nullptr, nullptr, 1.f, k2b);
  vtrans<<<dim3(16, 12), 256, 0, stream>>>(v2b, vtc, LCTX, LCTX);
  flash_attn<<<dim3(57, 12, 2), 256, 0, stream>>>(qb, k2b, vtc, ab,
      (float*)pre0, (float*)kb, (float2*)vts, S_LEN, LCTX, 256, LCTX);
  merge_o<<<RED_G, 256, 0, stream>>>(
      (const float*)pre0, (const float*)kb, (const float2*)vts, ab, S_LEN);
  // ca o-proj split-K x2: partials -> qb..kb (dead) and sa_qkvT region (dead)
  gemm_bt<6><<<dim3(29, 12, 2), 256, 0, stream>>>(ab, ca_owT, nullptr,
      (float*)qb, (float*)sa_qkvT, nullptr, S_LEN, DMODEL, DMODEL, 768);
  // fused: pre0 = x2 + (o + ca_ob); h_bf = LN(pre0)*(1+sc_mlp) + sh_mlp
  red2_ln<<<S_LEN, 256, 0, stream>>>((const float*)qb, (const float*)sa_qkvT,
      x2, nullptr, ca_ob, modc + 4 * DMODEL, modc + 3 * DMODEL, 1.f, pre0, h_bf);

  // ---- FFN ----
  gemm_bt<3><<<dim3(29, 70), 256, 0, stream>>>(h_bf, w1T, fb1,
      nullptr, nullptr, fmid, S_LEN, FFND, DMODEL, DMODEL);
  gemm_bt<5><<<dim3(29, 12, 2), 256, 0, stream>>>(fmid, w2T, nullptr,
      fpart, nullptr, nullptr, S_LEN, DMODEL, FFND, FFND / 2);
  red2<<<RED_G, 256, 0, stream>>>(fpart, fpart + (size_t)S_LEN * DMODEL,
      pre0, modc + 5 * DMODEL, fb2, out, S_LEN * DMODEL);
}

// Round 13
// 913.787 us; speedup vs baseline: 1.3178x; 1.0182x over previous
//
#include <hip/hip_runtime.h>
#include <cstdint>

#define S_LEN 3600
#define DMODEL 1536
#define LCTX 512
#define NH 12
#define HDIM 128
#define FFND 8960
#define SPAD_SELF 3648

typedef short v8s __attribute__((ext_vector_type(8)));
typedef float v4f __attribute__((ext_vector_type(4)));
typedef unsigned short u16b;
typedef unsigned int u32b;

#define AS1 __attribute__((address_space(1)))
#define AS3 __attribute__((address_space(3)))

__device__ __forceinline__ void gl_lds16(const void* g, void* l){
  __builtin_amdgcn_global_load_lds((AS1 const void*)g, (AS3 void*)l, 16, 0, 0);
}

__device__ __forceinline__ u16b f2b(float f){
  union { float f; u32b i; } x; x.f = f;
  u32b r = x.i + 0x7fffu + ((x.i >> 16) & 1u);
  return (u16b)(r >> 16);
}

__device__ __forceinline__ u32b cvtpk(float a, float b){
  u32b r;
  asm("v_cvt_pk_bf16_f32 %0, %1, %2" : "=v"(r) : "v"(a), "v"(b));
  return r;
}

__device__ __forceinline__ int swz4(int row){ return (row ^ (row >> 2)) & 3; }

// bijective XCD swizzle (m204)
__device__ __forceinline__ int xcd_swz(int orig, int nwg){
  int q8 = nwg >> 3, r8 = nwg & 7;
  int xcd = orig & 7, idx = orig >> 3;
  return (xcd < r8 ? xcd * (q8 + 1) : r8 * (q8 + 1) + (xcd - r8) * q8) + idx;
}

// ---------------- small elementwise kernels ----------------
__global__ void add_vec(const float* __restrict__ a, const float* __restrict__ b,
                        float* __restrict__ o, int n){
  int i = blockIdx.x * 256 + threadIdx.x;
  if (i < n) o[i] = a[i] + b[i];
}

__global__ void f2b_kernel(const float* __restrict__ in, u16b* __restrict__ out, int n){
  int i = blockIdx.x * 256 + threadIdx.x;
  if (i < n) out[i] = f2b(in[i]);
}

// ---------------- fused transpose-convert of all weights ----------------
struct WJob { const float* W; u16b* WT; int K; int N; int t0; };
struct WJobs { WJob j[10]; };

__global__ __launch_bounds__(256) void wconv(WJobs jobs){
  __shared__ float tile[32][33];
  int b = blockIdx.x;
  int ji = 0;
  #pragma unroll
  for (int i = 0; i < 10; ++i) if (b >= jobs.j[i].t0) ji = i;
  WJob jb = jobs.j[ji];
  int rel = b - jb.t0;
  int ntn = jb.N / 32;
  int k0 = (rel / ntn) * 32, n0 = (rel % ntn) * 32;
  int tx = threadIdx.x & 31, ty = threadIdx.x >> 5;
  #pragma unroll
  for (int r = ty; r < 32; r += 8) tile[r][tx] = jb.W[(size_t)(k0 + r) * jb.N + n0 + tx];
  __syncthreads();
  #pragma unroll
  for (int r = ty; r < 32; r += 8) jb.WT[(size_t)(n0 + r) * jb.K + k0 + tx] = f2b(tile[tx][r]);
}

// ---------------- per-head V transpose ----------------
__global__ __launch_bounds__(256) void vtrans(const u16b* __restrict__ V,
                                              u16b* __restrict__ Vt,
                                              int S, int Spad){
  __shared__ u16b t[32][136];
  int h = blockIdx.y, kb = blockIdx.x * 32, tid = threadIdx.x;
  int row = tid >> 3, ch = tid & 7;
  int key = kb + row;
  if (key < S){
    float4 a = *(const float4*)(V + (size_t)key * DMODEL + h * HDIM + ch * 16);
    float4 b = *(const float4*)(V + (size_t)key * DMODEL + h * HDIM + ch * 16 + 8);
    *(float4*)&t[row][ch * 16] = a;
    *(float4*)&t[row][ch * 16 + 8] = b;
  } else {
    float4 z = {0.f, 0.f, 0.f, 0.f};
    *(float4*)&t[row][ch * 16] = z;
    *(float4*)&t[row][ch * 16 + 8] = z;
  }
  __syncthreads();
  int hd = tid >> 1, kc = (tid & 1) * 16;
  u16b* dst = Vt + ((size_t)h * HDIM + hd) * Spad + kb + kc;
  #pragma unroll
  for (int e = 0; e < 16; e += 2){
    u32b pk = ((u32b)t[kc + e][hd]) | (((u32b)t[kc + e + 1][hd]) << 16);
    *(u32b*)(dst + e) = pk;
  }
}

// ---------------- LayerNorm (mod) -> bf16 ----------------
__global__ __launch_bounds__(256) void ln_mod(const float* __restrict__ X,
                                              const float* __restrict__ gamma,
                                              const float* __restrict__ beta,
                                              float gadd, u16b* __restrict__ out){
  int row = blockIdx.x;
  const float* xr = X + (size_t)row * DMODEL;
  int tid = threadIdx.x;
  float v[6]; float s1 = 0.f, s2 = 0.f;
  #pragma unroll
  for (int j = 0; j < 6; ++j){ v[j] = xr[tid + j * 256]; s1 += v[j]; s2 += v[j] * v[j]; }
  #pragma unroll
  for (int o = 1; o < 64; o <<= 1){ s1 += __shfl_xor(s1, o); s2 += __shfl_xor(s2, o); }
  __shared__ float red[8];
  int wid = tid >> 6, lane = tid & 63;
  if (!lane){ red[wid * 2] = s1; red[wid * 2 + 1] = s2; }
  __syncthreads();
  s1 = red[0] + red[2] + red[4] + red[6];
  s2 = red[1] + red[3] + red[5] + red[7];
  float mu = s1 / DMODEL;
  float var = s2 / DMODEL - mu * mu;
  float rstd = rsqrtf(var + 1e-6f);
  #pragma unroll
  for (int j = 0; j < 6; ++j){
    int c = tid + j * 256;
    out[(size_t)row * DMODEL + c] = f2b((v[j] - mu) * rstd * (gamma[c] + gadd) + beta[c]);
  }
}

// ---------------- fused: y = res + gate*(p0+p1+bias); h = LN(y)*gamma(+gadd)+beta ----------------
__global__ __launch_bounds__(256) void red2_ln(
    const float* __restrict__ p0, const float* __restrict__ p1,
    const float* __restrict__ res, const float* __restrict__ gate,
    const float* __restrict__ bias,
    const float* __restrict__ gamma, const float* __restrict__ beta, float gadd,
    float* __restrict__ yOut, u16b* __restrict__ hOut)
{
  int row = blockIdx.x, tid = threadIdx.x;
  size_t base = (size_t)row * DMODEL;
  float y[6]; float s1 = 0.f, s2 = 0.f;
  #pragma unroll
  for (int j = 0; j < 6; ++j){
    int c = tid + j * 256;
    float v = p0[base + c] + p1[base + c] + bias[c];
    if (gate) v *= gate[c];
    v += res[base + c];
    y[j] = v; s1 += v; s2 += v * v;
  }
  #pragma unroll
  for (int o = 1; o < 64; o <<= 1){ s1 += __shfl_xor(s1, o); s2 += __shfl_xor(s2, o); }
  __shared__ float red[8];
  int wid = tid >> 6, lane = tid & 63;
  if (!lane){ red[wid * 2] = s1; red[wid * 2 + 1] = s2; }
  __syncthreads();
  s1 = red[0] + red[2] + red[4] + red[6];
  s2 = red[1] + red[3] + red[5] + red[7];
  float mu = s1 / DMODEL;
  float var = s2 / DMODEL - mu * mu;
  float rstd = rsqrtf(var + 1e-6f);
  #pragma unroll
  for (int j = 0; j < 6; ++j){
    int c = tid + j * 256;
    yOut[base + c] = y[j];
    hOut[base + c] = f2b((y[j] - mu) * rstd * (gamma[c] + gadd) + beta[c]);
  }
}

// ---------------- RMSNorm (+optional RoPE) fp32 -> bf16 ----------------
__global__ __launch_bounds__(256) void rms_rope(const float* __restrict__ X,
                                                const float* __restrict__ w,
                                                const float* __restrict__ cosT,
                                                const float* __restrict__ sinT,
                                                float qmul,
                                                u16b* __restrict__ out){
  int row = blockIdx.x;
  const float* xr = X + (size_t)row * DMODEL;
  int tid = threadIdx.x;
  float2 v[3]; float ss = 0.f;
  #pragma unroll
  for (int j = 0; j < 3; ++j){
    v[j] = *(const float2*)(xr + 2 * (tid + j * 256));
    ss += v[j].x * v[j].x + v[j].y * v[j].y;
  }
  #pragma unroll
  for (int o = 1; o < 64; o <<= 1) ss += __shfl_xor(ss, o);
  __shared__ float red[4];
  int wid = tid >> 6, lane = tid & 63;
  if (!lane) red[wid] = ss;
  __syncthreads();
  ss = red[0] + red[1] + red[2] + red[3];
  float rstd = rsqrtf(ss / DMODEL + 1e-6f);
  #pragma unroll
  for (int j = 0; j < 3; ++j){
    int p = tid + j * 256;
    float xe = v[j].x * rstd * w[2 * p];
    float xo = v[j].y * rstd * w[2 * p + 1];
    float oe, oo;
    if (cosT){
      int d = p & 63;
      float c = cosT[row * 64 + d], sn = sinT[row * 64 + d];
      oe = xe * c - xo * sn; oo = xe * sn + xo * c;
    } else { oe = xe; oo = xo; }
    oe *= qmul; oo *= qmul;
    u32b packed = ((u32b)f2b(oe)) | (((u32b)f2b(oo)) << 16);
    *(u32b*)(out + (size_t)row * DMODEL + 2 * p) = packed;
  }
}

// ---------------- segment descriptors ----------------
struct Seg { const float* bias; float* outF; u16b* outB; };
struct Segs { Seg s[3]; };

// ---------------- 128x128 GEMM, 3-buffer counted-vmcnt pipeline ----------------
// EPI: 3 = gelu->bf16 (bias); 5 = split-K partial contiguous (outF + z*M*N);
//      6 = split-K partial two-pointer (z ? outF2 : outF)
template<int EPI>
__global__ __launch_bounds__(256, 2) void gemm_bt(
    const u16b* __restrict__ A, const u16b* __restrict__ BT,
    const float* __restrict__ bias, float* __restrict__ outF,
    float* __restrict__ outF2, u16b* __restrict__ outB,
    int M, int N, int K, int kLen)
{
  __shared__ char Ls[3][16384];
  const int tid = threadIdx.x, lane = tid & 63, wid = tid >> 6;
  const int nwg = gridDim.x * gridDim.y;
  const int swz = xcd_swz(blockIdx.x + gridDim.x * blockIdx.y, nwg);
  const int bm = (swz % gridDim.x) * 128, bn = (swz / gridDim.x) * 128;
  const int kbase = blockIdx.z * kLen;
  const int wm = (wid >> 1) * 64, wn = (wid & 1) * 64;
  v4f acc[4][4] = {};

  const u16b* pA[2]; const u16b* pB[2];
  #pragma unroll
  for (int c = 0; c < 2; ++c){
    int row = c * 64 + (tid >> 2);
    int col = (tid & 3) ^ swz4(row);
    pA[c] = A + (size_t)min(bm + row, M - 1) * K + kbase + col * 8;
    pB[c] = BT + (size_t)(bn + row) * K + kbase + col * 8;
  }
  auto stage = [&](int b){
    char* Lb = Ls[b];
    #pragma unroll
    for (int c = 0; c < 2; ++c){
      gl_lds16(pA[c], Lb + (c * 256 + tid) * 16);
      gl_lds16(pB[c], Lb + 8192 + (c * 256 + tid) * 16);
      pA[c] += 32; pB[c] += 32;
    }
  };

  const int chk = lane >> 4, qr = lane & 15;
  int offA[4], offB[4];
  #pragma unroll
  for (int f = 0; f < 4; ++f){
    int ra = wm + f * 16 + qr;
    offA[f] = ra * 64 + ((chk ^ swz4(ra)) * 16);
    int rb = wn + f * 16 + qr;
    offB[f] = 8192 + rb * 64 + ((chk ^ swz4(rb)) * 16);
  }

  const int nt = kLen / 32;
  stage(0); stage(1);
  int s = 0, sp = 2;
  for (int t = 0; t < nt; ++t){
    if (t + 1 < nt) asm volatile("s_waitcnt vmcnt(4)" ::: "memory");
    else            asm volatile("s_waitcnt vmcnt(0)" ::: "memory");
    __builtin_amdgcn_s_barrier();
    if (t + 2 < nt) stage(sp);
    char* Lb = Ls[s];
    v8s af[4], bfr[4];
    #pragma unroll
    for (int f = 0; f < 4; ++f){
      af[f] = *(const v8s*)(Lb + offA[f]);
      bfr[f] = *(const v8s*)(Lb + offB[f]);
    }
    __builtin_amdgcn_s_setprio(1);
    #pragma unroll
    for (int i = 0; i < 4; ++i)
      #pragma unroll
      for (int j = 0; j < 4; ++j)
        acc[i][j] = __builtin_amdgcn_mfma_f32_16x16x32_bf16(af[i], bfr[j], acc[i][j], 0, 0, 0);
    __builtin_amdgcn_s_setprio(0);
    s = (s == 2) ? 0 : s + 1;
    sp = (sp == 2) ? 0 : sp + 1;
  }
  const int rr = lane >> 4;
  float* op6 = (EPI == 6) ? (blockIdx.z ? outF2 : outF) : outF;
  #pragma unroll
  for (int i = 0; i < 4; ++i){
    #pragma unroll
    for (int j = 0; j < 4; ++j){
      int n = bn + wn + j * 16 + qr;
      float bv = (EPI == 3) ? bias[n] : 0.f;
      #pragma unroll
      for (int r = 0; r < 4; ++r){
        int m = bm + wm + i * 16 + rr * 4 + r;
        if (m < M){
          float val = acc[i][j][r] + bv;
          size_t idx = (size_t)m * N + n;
          if (EPI == 3){
            float t3 = val * val * val;
            float g = val / (1.f + __expf(-1.5957691216057308f * (val + 0.044715f * t3)));
            outB[idx] = f2b(g);
          } else if (EPI == 5){
            outF[(size_t)blockIdx.z * M * N + idx] = val;
          } else {
            op6[idx] = val;
          }
        }
      }
    }
  }
}

// ---------------- segmented 128^2 GEMM (QKV / ca K/V fused) ----------------
__global__ __launch_bounds__(256, 2) void gemm_seg(
    const u16b* __restrict__ A, const u16b* __restrict__ BT,
    Segs segs, int M, int N, int K)
{
  __shared__ char Ls[3][16384];
  const int tid = threadIdx.x, lane = tid & 63, wid = tid >> 6;
  const int nwg = gridDim.x * gridDim.y;
  const int swz = xcd_swz(blockIdx.x + gridDim.x * blockIdx.y, nwg);
  const int bm = (swz % gridDim.x) * 128, bn = (swz / gridDim.x) * 128;
  const int wm = (wid >> 1) * 64, wn = (wid & 1) * 64;
  v4f acc[4][4] = {};

  const u16b* pA[2]; const u16b* pB[2];
  #pragma unroll
  for (int c = 0; c < 2; ++c){
    int row = c * 64 + (tid >> 2);
    int col = (tid & 3) ^ swz4(row);
    pA[c] = A + (size_t)min(bm + row, M - 1) * K + col * 8;
    pB[c] = BT + (size_t)(bn + row) * K + col * 8;
  }
  auto stage = [&](int b){
    char* Lb = Ls[b];
    #pragma unroll
    for (int c = 0; c < 2; ++c){
      gl_lds16(pA[c], Lb + (c * 256 + tid) * 16);
      gl_lds16(pB[c], Lb + 8192 + (c * 256 + tid) * 16);
      pA[c] += 32; pB[c] += 32;
    }
  };

  const int chk = lane >> 4, qr = lane & 15;
  int offA[4], offB[4];
  #pragma unroll
  for (int f = 0; f < 4; ++f){
    int ra = wm + f * 16 + qr;
    offA[f] = ra * 64 + ((chk ^ swz4(ra)) * 16);
    int rb = wn + f * 16 + qr;
    offB[f] = 8192 + rb * 64 + ((chk ^ swz4(rb)) * 16);
  }

  const int nt = K / 32;
  stage(0); stage(1);
  int s = 0, sp = 2;
  for (int t = 0; t < nt; ++t){
    if (t + 1 < nt) asm volatile("s_waitcnt vmcnt(4)" ::: "memory");
    else            asm volatile("s_waitcnt vmcnt(0)" ::: "memory");
    __builtin_amdgcn_s_barrier();
    if (t + 2 < nt) stage(sp);
    char* Lb = Ls[s];
    v8s af[4], bfr[4];
    #pragma unroll
    for (int f = 0; f < 4; ++f){
      af[f] = *(const v8s*)(Lb + offA[f]);
      bfr[f] = *(const v8s*)(Lb + offB[f]);
    }
    __builtin_amdgcn_s_setprio(1);
    #pragma unroll
    for (int i = 0; i < 4; ++i)
      #pragma unroll
      for (int j = 0; j < 4; ++j)
        acc[i][j] = __builtin_amdgcn_mfma_f32_16x16x32_bf16(af[i], bfr[j], acc[i][j], 0, 0, 0);
    __builtin_amdgcn_s_setprio(0);
    s = (s == 2) ? 0 : s + 1;
    sp = (sp == 2) ? 0 : sp + 1;
  }
  const int seg = bn / 1536;
  const Seg sg = segs.s[seg];
  const int rr = lane >> 4;
  #pragma unroll
  for (int i = 0; i < 4; ++i){
    #pragma unroll
    for (int j = 0; j < 4; ++j){
      int nloc = bn - seg * 1536 + wn + j * 16 + qr;
      float bv = sg.bias[nloc];
      #pragma unroll
      for (int r = 0; r < 4; ++r){
        int m = bm + wm + i * 16 + rr * 4 + r;
        if (m < M){
          float val = acc[i][j][r] + bv;
          size_t idx = (size_t)m * 1536 + nloc;
          if (sg.outB) sg.outB[idx] = f2b(val);
          else sg.outF[idx] = val;
        }
      }
    }
  }
}

// ---------------- split-K x2 reduce: out = res? + gate? * (p0+p1+bias) ----------------
__global__ __launch_bounds__(256) void red2(const float* __restrict__ p0,
                                            const float* __restrict__ p1,
                                            const float* __restrict__ res,
                                            const float* __restrict__ gate,
                                            const float* __restrict__ bias,
                                            float* __restrict__ out, int total){
  int i4 = blockIdx.x * 256 + threadIdx.x;
  if (i4 * 4 >= total) return;
  int base = i4 * 4, n = base % DMODEL;
  float4 a = *(const float4*)(p0 + base);
  float4 b = *(const float4*)(p1 + base);
  float4 bv = *(const float4*)(bias + n);
  float gx = 1.f, gy = 1.f, gz = 1.f, gw = 1.f;
  if (gate){ float4 g = *(const float4*)(gate + n); gx = g.x; gy = g.y; gz = g.z; gw = g.w; }
  float rx = 0.f, ry = 0.f, rz = 0.f, rw = 0.f;
  if (res){ float4 r = *(const float4*)(res + base); rx = r.x; ry = r.y; rz = r.z; rw = r.w; }
  float4 o;
  o.x = rx + gx * (a.x + b.x + bv.x);
  o.y = ry + gy * (a.y + b.y + bv.y);
  o.z = rz + gz * (a.z + b.z + bv.z);
  o.w = rw + gw * (a.w + b.w + bv.w);
  *(float4*)(out + base) = o;
}

// ---------------- flash attention: KVBLK=64, single KV buffer, no key-split ----------------
__global__ __launch_bounds__(256, 4) void flash_attn(
    const u16b* __restrict__ Q, const u16b* __restrict__ Kp,
    const u16b* __restrict__ Vt, u16b* __restrict__ O,
    int Sq, int Sk, int Spad)
{
  __shared__ char KV[32768];
  __shared__ char Pall[8192];
  const int tid = threadIdx.x, lane = tid & 63, wid = tid >> 6;
  const int h = blockIdx.y;
  const int q0 = blockIdx.x * 64 + wid * 16;
  const int qq = lane & 15, cc = lane >> 4;
  char* Kb = KV; char* Vb = KV + 16384;
  char* Pb = Pall + wid * 2048;

  v8s qf[4];
  {
    int qrow = min(q0 + qq, Sq - 1);
    const u16b* qp = Q + (size_t)qrow * DMODEL + h * HDIM + cc * 8;
    #pragma unroll
    for (int ks = 0; ks < 4; ++ks) qf[ks] = *(const v8s*)(qp + ks * 32);
  }

  auto stage = [&](int kb0){
    #pragma unroll
    for (int c = 0; c < 4; ++c){
      int seg = wid * 4 + c;
      int g = seg * 64 + lane;
      int krow = g >> 4, kcol = (g & 15) ^ (krow & 7);
      gl_lds16(Kp + (size_t)min(kb0 + krow, Sk - 1) * DMODEL + h * HDIM + kcol * 8,
               Kb + seg * 1024);
      int vrow = g >> 3, vcol = (g & 7) ^ (vrow & 7);
      gl_lds16(Vt + ((size_t)h * HDIM + vrow) * Spad + kb0 + vcol * 8,
               Vb + seg * 1024);
    }
  };

  float mrun = -1e30f, lrun = 0.f;
  v4f oacc[8] = {};
  const int nt = (Sk + 63) >> 6;

  for (int t = 0; t < nt; ++t){
    int kb0 = t << 6;
    stage(kb0);
    __syncthreads();
    v4f sc[4];
    __builtin_amdgcn_s_setprio(1);
    #pragma unroll
    for (int sub = 0; sub < 4; ++sub){
      v4f sa = {0.f, 0.f, 0.f, 0.f};
      int row = sub * 16 + qq;
      #pragma unroll
      for (int ks = 0; ks < 4; ++ks){
        v8s kf = *(const v8s*)(Kb + row * 256 + (((ks * 4 + cc) ^ (row & 7)) * 16));
        sa = __builtin_amdgcn_mfma_f32_16x16x32_bf16(kf, qf[ks], sa, 0, 0, 0);
      }
      sc[sub] = sa;
    }
    __builtin_amdgcn_s_setprio(0);
    if (kb0 + 64 > Sk){
      #pragma unroll
      for (int sub = 0; sub < 4; ++sub)
        #pragma unroll
        for (int r = 0; r < 4; ++r)
          if (kb0 + sub * 16 + cc * 4 + r >= Sk) sc[sub][r] = -1e30f;
    }
    float m01 = fmaxf(fmaxf(sc[0][0], sc[0][1]), fmaxf(sc[0][2], sc[0][3]));
    float m23 = fmaxf(fmaxf(sc[1][0], sc[1][1]), fmaxf(sc[1][2], sc[1][3]));
    float m45 = fmaxf(fmaxf(sc[2][0], sc[2][1]), fmaxf(sc[2][2], sc[2][3]));
    float m67 = fmaxf(fmaxf(sc[3][0], sc[3][1]), fmaxf(sc[3][2], sc[3][3]));
    float pmax = fmaxf(fmaxf(m01, m23), fmaxf(m45, m67));
    pmax = fmaxf(pmax, __shfl_xor(pmax, 16));
    pmax = fmaxf(pmax, __shfl_xor(pmax, 32));
    if (!__all(pmax <= mrun + 11.54f)){
      float mnew = fmaxf(mrun, pmax);
      float alpha = exp2f(mrun - mnew);
      mrun = mnew;
      float alr[4];
      #pragma unroll
      for (int r = 0; r < 4; ++r) alr[r] = __shfl(alpha, cc * 4 + r);
      #pragma unroll
      for (int f = 0; f < 8; ++f)
        #pragma unroll
        for (int r = 0; r < 4; ++r) oacc[f][r] *= alr[r];
      lrun *= alpha;
    }
    float csum = 0.f;
    #pragma unroll
    for (int sub = 0; sub < 4; ++sub){
      float s0 = 0.f, s1 = 0.f;
      #pragma unroll
      for (int r = 0; r < 4; r += 2){
        float p0 = exp2f(sc[sub][r] - mrun);
        float p1 = exp2f(sc[sub][r + 1] - mrun);
        sc[sub][r] = p0; sc[sub][r + 1] = p1;
        s0 += p0; s1 += p1;
      }
      csum += s0 + s1;
    }
    csum += __shfl_xor(csum, 16);
    csum += __shfl_xor(csum, 32);
    lrun += csum;
    #pragma unroll
    for (int sub = 0; sub < 4; ++sub){
      uint2 w2;
      w2.x = cvtpk(sc[sub][0], sc[sub][1]);
      w2.y = cvtpk(sc[sub][2], sc[sub][3]);
      int gI = sub * 2 + (cc >> 1);
      *(uint2*)(Pb + qq * 128 + ((gI ^ (qq & 7)) * 16) + (cc & 1) * 8) = w2;
    }
    v8s pf0 = *(const v8s*)(Pb + qq * 128 + (((cc) ^ (qq & 7)) * 16));
    v8s pf1 = *(const v8s*)(Pb + qq * 128 + (((4 + cc) ^ (qq & 7)) * 16));
    __builtin_amdgcn_s_setprio(1);
    #pragma unroll
    for (int hdb = 0; hdb < 8; ++hdb){
      int row = hdb * 16 + qq;
      v8s vf0 = *(const v8s*)(Vb + row * 128 + (((cc) ^ (row & 7)) * 16));
      v8s vf1 = *(const v8s*)(Vb + row * 128 + (((4 + cc) ^ (row & 7)) * 16));
      oacc[hdb] = __builtin_amdgcn_mfma_f32_16x16x32_bf16(pf0, vf0, oacc[hdb], 0, 0, 0);
      oacc[hdb] = __builtin_amdgcn_mfma_f32_16x16x32_bf16(pf1, vf1, oacc[hdb], 0, 0, 0);
    }
    __builtin_amdgcn_s_setprio(0);
    __syncthreads();
  }

  float linv = 1.f / lrun;
  float lr[4];
  #pragma unroll
  for (int r = 0; r < 4; ++r) lr[r] = __shfl(linv, cc * 4 + r);
  #pragma unroll
  for (int hdb = 0; hdb < 8; ++hdb)
    #pragma unroll
    for (int r = 0; r < 4; ++r){
      int qrow = q0 + cc * 4 + r;
      if (qrow < Sq)
        O[(size_t)qrow * DMODEL + h * HDIM + hdb * 16 + qq] = f2b(oacc[hdb][r] * lr[r]);
    }
}

// ---------------- host launch ----------------
extern "C" void kernel_launch(void* const* d_in, const int* in_sizes, int n_in,
                              void* d_out, int out_size, void* d_ws, size_t ws_size,
                              hipStream_t stream){
  (void)in_sizes; (void)n_in; (void)out_size; (void)ws_size;
  const float* x     = (const float*)d_in[0];
  const float* ctx   = (const float*)d_in[1];
  const float* t_mod = (const float*)d_in[2];
  const float* ropec = (const float*)d_in[3];
  const float* ropes = (const float*)d_in[4];
  const float* modu  = (const float*)d_in[5];
  const float* sa_qw = (const float*)d_in[6];  const float* sa_qb = (const float*)d_in[7];
  const float* sa_kw = (const float*)d_in[8];  const float* sa_kb = (const float*)d_in[9];
  const float* sa_vw = (const float*)d_in[10]; const float* sa_vb = (const float*)d_in[11];
  const float* sa_ow = (const float*)d_in[12]; const float* sa_ob = (const float*)d_in[13];
  const float* sa_nq = (const float*)d_in[14]; const float* sa_nk = (const float*)d_in[15];
  const float* ca_qw = (const float*)d_in[16]; const float* ca_qb = (const float*)d_in[17];
  const float* ca_kw = (const float*)d_in[18]; const float* ca_kb = (const float*)d_in[19];
  const float* ca_vw = (const float*)d_in[20]; const float* ca_vb = (const float*)d_in[21];
  const float* ca_ow = (const float*)d_in[22]; const float* ca_ob = (const float*)d_in[23];
  const float* ca_nq = (const float*)d_in[24]; const float* ca_nk = (const float*)d_in[25];
  const float* n3w   = (const float*)d_in[26]; const float* n3b   = (const float*)d_in[27];
  const float* fw1   = (const float*)d_in[28]; const float* fb1   = (const float*)d_in[29];
  const float* fw2   = (const float*)d_in[30]; const float* fb2   = (const float*)d_in[31];
  float* out = (float*)d_out;

  const float QSCALE = 0.08838834764831845f * 1.4426950408889634f;

  char* wsp = (char*)d_ws;
  size_t off = 0;
  auto alloc = [&](size_t b){ void* p = wsp + off; off += (b + 255) & ~(size_t)255; return p; };
  const size_t WW = (size_t)DMODEL * DMODEL * 2;
  float* modc = (float*)alloc(6 * DMODEL * 4);
  u16b* w1T   = (u16b*)alloc((size_t)FFND * DMODEL * 2);
  u16b* w2T   = (u16b*)alloc((size_t)DMODEL * FFND * 2);
  u16b* h_bf  = (u16b*)alloc((size_t)S_LEN * DMODEL * 2);
  float* pre0 = (float*)alloc((size_t)S_LEN * DMODEL * 4);
  size_t region0 = off;
  u16b* sa_qkvT = (u16b*)alloc(3 * WW);
  u16b* sa_owT  = (u16b*)alloc(WW);
  u16b* ca_qwT  = (u16b*)alloc(WW);
  u16b* ca_kvT  = (u16b*)alloc(2 * WW);
  u16b* ca_owT  = (u16b*)alloc(WW);
  float* x2    = (float*)alloc((size_t)S_LEN * DMODEL * 4);
  float* pre2  = (float*)alloc((size_t)LCTX * DMODEL * 4);
  u16b* qb     = (u16b*)alloc((size_t)S_LEN * DMODEL * 2);   // qb..kb = 22.1MB f32-partial span
  u16b* kb     = (u16b*)alloc((size_t)S_LEN * DMODEL * 2);
  u16b* vb     = (u16b*)alloc((size_t)S_LEN * DMODEL * 2);   // vb..ab = 22.1MB f32-partial span
  u16b* ab     = (u16b*)alloc((size_t)S_LEN * DMODEL * 2);
  u16b* ctxb   = (u16b*)alloc((size_t)LCTX * DMODEL * 2);
  u16b* k2b    = (u16b*)alloc((size_t)LCTX * DMODEL * 2);
  u16b* v2b    = (u16b*)alloc((size_t)LCTX * DMODEL * 2);
  u16b* vts    = (u16b*)alloc((size_t)NH * HDIM * SPAD_SELF * 2);
  u16b* vtc    = (u16b*)alloc((size_t)NH * HDIM * LCTX * 2);
  u16b* fmid = (u16b*)(wsp + region0);
  float* fpart = (float*)(wsp + region0 + (size_t)S_LEN * FFND * 2);

  add_vec<<<36, 256, 0, stream>>>(modu, t_mod, modc, 6 * DMODEL);

  WJobs jobs; int t = 0;
  auto addjob = [&](int i, const float* w_, u16b* wt, int K, int N){
    jobs.j[i].W = w_; jobs.j[i].WT = wt; jobs.j[i].K = K; jobs.j[i].N = N; jobs.j[i].t0 = t;
    t += (K / 32) * (N / 32);
  };
  addjob(0, sa_qw, sa_qkvT, DMODEL, DMODEL);
  addjob(1, sa_kw, sa_qkvT + (size_t)DMODEL * DMODEL, DMODEL, DMODEL);
  addjob(2, sa_vw, sa_qkvT + (size_t)2 * DMODEL * DMODEL, DMODEL, DMODEL);
  addjob(3, sa_ow, sa_owT, DMODEL, DMODEL);
  addjob(4, ca_qw, ca_qwT, DMODEL, DMODEL);
  addjob(5, ca_kw, ca_kvT, DMODEL, DMODEL);
  addjob(6, ca_vw, ca_kvT + (size_t)DMODEL * DMODEL, DMODEL, DMODEL);
  addjob(7, ca_ow, ca_owT, DMODEL, DMODEL);
  addjob(8, fw1, w1T, DMODEL, FFND);
  addjob(9, fw2, w2T, FFND, DMODEL);
  wconv<<<t, 256, 0, stream>>>(jobs);

  f2b_kernel<<<(LCTX * DMODEL) / 256, 256, 0, stream>>>(ctx, ctxb, LCTX * DMODEL);

  const int RED_G = (S_LEN * DMODEL / 4 + 255) / 256;

  // ---- self attention branch ----
  ln_mod<<<S_LEN, 256, 0, stream>>>(x, modc + DMODEL, modc, 1.f, h_bf);
  {
    Segs sg;
    sg.s[0] = { sa_qb, pre0, nullptr };
    sg.s[1] = { sa_kb, x2,   nullptr };
    sg.s[2] = { sa_vb, nullptr, vb   };
    gemm_seg<<<dim3(29, 36), 256, 0, stream>>>(h_bf, sa_qkvT, sg, S_LEN, 3 * DMODEL, DMODEL);
  }
  rms_rope<<<S_LEN, 256, 0, stream>>>(pre0, sa_nq, ropec, ropes, QSCALE, qb);
  rms_rope<<<S_LEN, 256, 0, stream>>>(x2, sa_nk, ropec, ropes, 1.f, kb);
  vtrans<<<dim3(SPAD_SELF / 32, 12), 256, 0, stream>>>(vb, vts, S_LEN, SPAD_SELF);
  flash_attn<<<dim3(57, 12), 256, 0, stream>>>(qb, kb, vts, ab, S_LEN, S_LEN, SPAD_SELF);
  // sa o-proj split-K x2: partials -> pre0 (dead) and qb..kb span (dead)
  gemm_bt<6><<<dim3(29, 12, 2), 256, 0, stream>>>(ab, sa_owT, nullptr,
      (float*)pre0, (float*)qb, nullptr, S_LEN, DMODEL, DMODEL, 768);
  // fused: x2 = x + g_msa*(o + sa_ob); h_bf = LN(x2)*n3w + n3b
  red2_ln<<<S_LEN, 256, 0, stream>>>((const float*)pre0, (const float*)qb,
      x, modc + 2 * DMODEL, sa_ob, n3w, n3b, 0.f, x2, h_bf);

  // ---- cross attention branch ----
  // ca_q split-K x2: partials -> qb..kb (dead) and vb..ab (dead)
  gemm_bt<6><<<dim3(29, 12, 2), 256, 0, stream>>>(h_bf, ca_qwT, nullptr,
      (float*)qb, (float*)vb, nullptr, S_LEN, DMODEL, DMODEL, 768);
  red2<<<RED_G, 256, 0, stream>>>((const float*)qb, (const float*)vb,
      nullptr, nullptr, ca_qb, pre0, S_LEN * DMODEL);
  {
    Segs sg;
    sg.s[0] = { ca_kb, pre2, nullptr };
    sg.s[1] = { ca_vb, nullptr, v2b  };
    sg.s[2] = { ca_vb, nullptr, v2b  };
    gemm_seg<<<dim3(4, 24), 256, 0, stream>>>(ctxb, ca_kvT, sg, LCTX, 2 * DMODEL, DMODEL);
  }
  rms_rope<<<S_LEN, 256, 0, stream>>>(pre0, ca_nq, nullptr, nullptr, QSCALE, qb);
  rms_rope<<<LCTX, 256, 0, stream>>>(pre2, ca_nk, nullptr, nullptr, 1.f, k2b);
  vtrans<<<dim3(16, 12), 256, 0, stream>>>(v2b, vtc, LCTX, LCTX);
  flash_attn<<<dim3(57, 12), 256, 0, stream>>>(qb, k2b, vtc, ab, S_LEN, LCTX, LCTX);
  // ca o-proj split-K x2: partials -> qb..kb (dead) and sa_qkvT region (dead)
  gemm_bt<6><<<dim3(29, 12, 2), 256, 0, stream>>>(ab, ca_owT, nullptr,
      (float*)qb, (float*)sa_qkvT, nullptr, S_LEN, DMODEL, DMODEL, 768);
  // fused: pre0 = x2 + (o + ca_ob); h_bf = LN(pre0)*(1+sc_mlp) + sh_mlp
  red2_ln<<<S_LEN, 256, 0, stream>>>((const float*)qb, (const float*)sa_qkvT,
      x2, nullptr, ca_ob, modc + 4 * DMODEL, modc + 3 * DMODEL, 1.f, pre0, h_bf);

  // ---- FFN ----
  gemm_bt<3><<<dim3(29, 70), 256, 0, stream>>>(h_bf, w1T, fb1,
      nullptr, nullptr, fmid, S_LEN, FFND, DMODEL, DMODEL);
  gemm_bt<5><<<dim3(29, 12, 2), 256, 0, stream>>>(fmid, w2T, nullptr,
      fpart, nullptr, nullptr, S_LEN, DMODEL, FFND, FFND / 2);
  red2<<<RED_G, 256, 0, stream>>>(fpart, fpart + (size_t)S_LEN * DMODEL,
      pre0, modc + 5 * DMODEL, fb2, out, S_LEN * DMODEL);
}

// Round 14
// 893.278 us; speedup vs baseline: 1.3481x; 1.0230x over previous
//
#include <hip/hip_runtime.h>
#include <cstdint>

#define S_LEN 3600
#define DMODEL 1536
#define LCTX 512
#define NH 12
#define HDIM 128
#define FFND 8960
#define SPAD_SELF 3648

typedef short v8s __attribute__((ext_vector_type(8)));
typedef float v4f __attribute__((ext_vector_type(4)));
typedef unsigned short u16b;
typedef unsigned int u32b;

#define AS1 __attribute__((address_space(1)))
#define AS3 __attribute__((address_space(3)))

__device__ __forceinline__ void gl_lds16(const void* g, void* l){
  __builtin_amdgcn_global_load_lds((AS1 const void*)g, (AS3 void*)l, 16, 0, 0);
}

__device__ __forceinline__ u16b f2b(float f){
  union { float f; u32b i; } x; x.f = f;
  u32b r = x.i + 0x7fffu + ((x.i >> 16) & 1u);
  return (u16b)(r >> 16);
}

__device__ __forceinline__ u32b cvtpk(float a, float b){
  u32b r;
  asm("v_cvt_pk_bf16_f32 %0, %1, %2" : "=v"(r) : "v"(a), "v"(b));
  return r;
}

__device__ __forceinline__ int swz4(int row){ return (row ^ (row >> 2)) & 3; }

// bijective XCD swizzle (m204)
__device__ __forceinline__ int xcd_swz(int orig, int nwg){
  int q8 = nwg >> 3, r8 = nwg & 7;
  int xcd = orig & 7, idx = orig >> 3;
  return (xcd < r8 ? xcd * (q8 + 1) : r8 * (q8 + 1) + (xcd - r8) * q8) + idx;
}

// ---------------- small elementwise kernels ----------------
__global__ void add_vec(const float* __restrict__ a, const float* __restrict__ b,
                        float* __restrict__ o, int n){
  int i = blockIdx.x * 256 + threadIdx.x;
  if (i < n) o[i] = a[i] + b[i];
}

__global__ void f2b_kernel(const float* __restrict__ in, u16b* __restrict__ out, int n){
  int i = blockIdx.x * 256 + threadIdx.x;
  if (i < n) out[i] = f2b(in[i]);
}

// ---------------- fused transpose-convert of all weights ----------------
struct WJob { const float* W; u16b* WT; int K; int N; int t0; };
struct WJobs { WJob j[10]; };

__global__ __launch_bounds__(256) void wconv(WJobs jobs){
  __shared__ float tile[32][33];
  int b = blockIdx.x;
  int ji = 0;
  #pragma unroll
  for (int i = 0; i < 10; ++i) if (b >= jobs.j[i].t0) ji = i;
  WJob jb = jobs.j[ji];
  int rel = b - jb.t0;
  int ntn = jb.N / 32;
  int k0 = (rel / ntn) * 32, n0 = (rel % ntn) * 32;
  int tx = threadIdx.x & 31, ty = threadIdx.x >> 5;
  #pragma unroll
  for (int r = ty; r < 32; r += 8) tile[r][tx] = jb.W[(size_t)(k0 + r) * jb.N + n0 + tx];
  __syncthreads();
  #pragma unroll
  for (int r = ty; r < 32; r += 8) jb.WT[(size_t)(n0 + r) * jb.K + k0 + tx] = f2b(tile[tx][r]);
}

// ---------------- per-head V transpose ----------------
__global__ __launch_bounds__(256) void vtrans(const u16b* __restrict__ V,
                                              u16b* __restrict__ Vt,
                                              int S, int Spad){
  __shared__ u16b t[32][136];
  int h = blockIdx.y, kb = blockIdx.x * 32, tid = threadIdx.x;
  int row = tid >> 3, ch = tid & 7;
  int key = kb + row;
  if (key < S){
    float4 a = *(const float4*)(V + (size_t)key * DMODEL + h * HDIM + ch * 16);
    float4 b = *(const float4*)(V + (size_t)key * DMODEL + h * HDIM + ch * 16 + 8);
    *(float4*)&t[row][ch * 16] = a;
    *(float4*)&t[row][ch * 16 + 8] = b;
  } else {
    float4 z = {0.f, 0.f, 0.f, 0.f};
    *(float4*)&t[row][ch * 16] = z;
    *(float4*)&t[row][ch * 16 + 8] = z;
  }
  __syncthreads();
  int hd = tid >> 1, kc = (tid & 1) * 16;
  u16b* dst = Vt + ((size_t)h * HDIM + hd) * Spad + kb + kc;
  #pragma unroll
  for (int e = 0; e < 16; e += 2){
    u32b pk = ((u32b)t[kc + e][hd]) | (((u32b)t[kc + e + 1][hd]) << 16);
    *(u32b*)(dst + e) = pk;
  }
}

// ---------------- LayerNorm (mod) -> bf16 ----------------
__global__ __launch_bounds__(256) void ln_mod(const float* __restrict__ X,
                                              const float* __restrict__ gamma,
                                              const float* __restrict__ beta,
                                              float gadd, u16b* __restrict__ out){
  int row = blockIdx.x;
  const float* xr = X + (size_t)row * DMODEL;
  int tid = threadIdx.x;
  float v[6]; float s1 = 0.f, s2 = 0.f;
  #pragma unroll
  for (int j = 0; j < 6; ++j){ v[j] = xr[tid + j * 256]; s1 += v[j]; s2 += v[j] * v[j]; }
  #pragma unroll
  for (int o = 1; o < 64; o <<= 1){ s1 += __shfl_xor(s1, o); s2 += __shfl_xor(s2, o); }
  __shared__ float red[8];
  int wid = tid >> 6, lane = tid & 63;
  if (!lane){ red[wid * 2] = s1; red[wid * 2 + 1] = s2; }
  __syncthreads();
  s1 = red[0] + red[2] + red[4] + red[6];
  s2 = red[1] + red[3] + red[5] + red[7];
  float mu = s1 / DMODEL;
  float var = s2 / DMODEL - mu * mu;
  float rstd = rsqrtf(var + 1e-6f);
  #pragma unroll
  for (int j = 0; j < 6; ++j){
    int c = tid + j * 256;
    out[(size_t)row * DMODEL + c] = f2b((v[j] - mu) * rstd * (gamma[c] + gadd) + beta[c]);
  }
}

// ---------------- fused: y = res + gate*(p0+p1+bias); h = LN(y)*gamma(+gadd)+beta ----------------
__global__ __launch_bounds__(256) void red2_ln(
    const float* __restrict__ p0, const float* __restrict__ p1,
    const float* __restrict__ res, const float* __restrict__ gate,
    const float* __restrict__ bias,
    const float* __restrict__ gamma, const float* __restrict__ beta, float gadd,
    float* __restrict__ yOut, u16b* __restrict__ hOut)
{
  int row = blockIdx.x, tid = threadIdx.x;
  size_t base = (size_t)row * DMODEL;
  float y[6]; float s1 = 0.f, s2 = 0.f;
  #pragma unroll
  for (int j = 0; j < 6; ++j){
    int c = tid + j * 256;
    float v = p0[base + c] + p1[base + c] + bias[c];
    if (gate) v *= gate[c];
    v += res[base + c];
    y[j] = v; s1 += v; s2 += v * v;
  }
  #pragma unroll
  for (int o = 1; o < 64; o <<= 1){ s1 += __shfl_xor(s1, o); s2 += __shfl_xor(s2, o); }
  __shared__ float red[8];
  int wid = tid >> 6, lane = tid & 63;
  if (!lane){ red[wid * 2] = s1; red[wid * 2 + 1] = s2; }
  __syncthreads();
  s1 = red[0] + red[2] + red[4] + red[6];
  s2 = red[1] + red[3] + red[5] + red[7];
  float mu = s1 / DMODEL;
  float var = s2 / DMODEL - mu * mu;
  float rstd = rsqrtf(var + 1e-6f);
  #pragma unroll
  for (int j = 0; j < 6; ++j){
    int c = tid + j * 256;
    yOut[base + c] = y[j];
    hOut[base + c] = f2b((y[j] - mu) * rstd * (gamma[c] + gadd) + beta[c]);
  }
}

// ---------------- fused: y = p0+p1+bias; out = RMS(y)*w*qmul -> bf16 (ca_q path) ----------------
__global__ __launch_bounds__(256) void red2_rms(
    const float* __restrict__ p0, const float* __restrict__ p1,
    const float* __restrict__ bias, const float* __restrict__ w,
    float qmul, u16b* __restrict__ out)
{
  int row = blockIdx.x, tid = threadIdx.x;
  size_t base = (size_t)row * DMODEL;
  float y[6]; float ss = 0.f;
  #pragma unroll
  for (int j = 0; j < 6; ++j){
    int c = tid + j * 256;
    float v = p0[base + c] + p1[base + c] + bias[c];
    y[j] = v; ss += v * v;
  }
  #pragma unroll
  for (int o = 1; o < 64; o <<= 1) ss += __shfl_xor(ss, o);
  __shared__ float red[4];
  int wid = tid >> 6, lane = tid & 63;
  if (!lane) red[wid] = ss;
  __syncthreads();
  ss = red[0] + red[1] + red[2] + red[3];
  float rstd = rsqrtf(ss / DMODEL + 1e-6f);
  #pragma unroll
  for (int j = 0; j < 6; ++j){
    int c = tid + j * 256;
    out[base + c] = f2b(y[j] * rstd * w[c] * qmul);
  }
}

// ---------------- RMSNorm (+optional RoPE) fp32 -> bf16 ----------------
__global__ __launch_bounds__(256) void rms_rope(const float* __restrict__ X,
                                                const float* __restrict__ w,
                                                const float* __restrict__ cosT,
                                                const float* __restrict__ sinT,
                                                float qmul,
                                                u16b* __restrict__ out){
  int row = blockIdx.x;
  const float* xr = X + (size_t)row * DMODEL;
  int tid = threadIdx.x;
  float2 v[3]; float ss = 0.f;
  #pragma unroll
  for (int j = 0; j < 3; ++j){
    v[j] = *(const float2*)(xr + 2 * (tid + j * 256));
    ss += v[j].x * v[j].x + v[j].y * v[j].y;
  }
  #pragma unroll
  for (int o = 1; o < 64; o <<= 1) ss += __shfl_xor(ss, o);
  __shared__ float red[4];
  int wid = tid >> 6, lane = tid & 63;
  if (!lane) red[wid] = ss;
  __syncthreads();
  ss = red[0] + red[1] + red[2] + red[3];
  float rstd = rsqrtf(ss / DMODEL + 1e-6f);
  #pragma unroll
  for (int j = 0; j < 3; ++j){
    int p = tid + j * 256;
    float xe = v[j].x * rstd * w[2 * p];
    float xo = v[j].y * rstd * w[2 * p + 1];
    float oe, oo;
    if (cosT){
      int d = p & 63;
      float c = cosT[row * 64 + d], sn = sinT[row * 64 + d];
      oe = xe * c - xo * sn; oo = xe * sn + xo * c;
    } else { oe = xe; oo = xo; }
    oe *= qmul; oo *= qmul;
    u32b packed = ((u32b)f2b(oe)) | (((u32b)f2b(oo)) << 16);
    *(u32b*)(out + (size_t)row * DMODEL + 2 * p) = packed;
  }
}

// ---------------- dual RMS+RoPE: y==0 -> (Xq, wq, QSCALE, outq); y==1 -> (Xk, wk, 1, outk) ----------------
__global__ __launch_bounds__(256) void rms_rope2(
    const float* __restrict__ Xq, const float* __restrict__ Xk,
    const float* __restrict__ wq, const float* __restrict__ wk,
    const float* __restrict__ cosT, const float* __restrict__ sinT,
    float qscale, u16b* __restrict__ outq, u16b* __restrict__ outk)
{
  int row = blockIdx.x;
  const float* X = blockIdx.y ? Xk : Xq;
  const float* w = blockIdx.y ? wk : wq;
  u16b* out = blockIdx.y ? outk : outq;
  float qmul = blockIdx.y ? 1.f : qscale;
  const float* xr = X + (size_t)row * DMODEL;
  int tid = threadIdx.x;
  float2 v[3]; float ss = 0.f;
  #pragma unroll
  for (int j = 0; j < 3; ++j){
    v[j] = *(const float2*)(xr + 2 * (tid + j * 256));
    ss += v[j].x * v[j].x + v[j].y * v[j].y;
  }
  #pragma unroll
  for (int o = 1; o < 64; o <<= 1) ss += __shfl_xor(ss, o);
  __shared__ float red[4];
  int wid = tid >> 6, lane = tid & 63;
  if (!lane) red[wid] = ss;
  __syncthreads();
  ss = red[0] + red[1] + red[2] + red[3];
  float rstd = rsqrtf(ss / DMODEL + 1e-6f);
  #pragma unroll
  for (int j = 0; j < 3; ++j){
    int p = tid + j * 256;
    float xe = v[j].x * rstd * w[2 * p];
    float xo = v[j].y * rstd * w[2 * p + 1];
    int d = p & 63;
    float c = cosT[row * 64 + d], sn = sinT[row * 64 + d];
    float oe = (xe * c - xo * sn) * qmul;
    float oo = (xe * sn + xo * c) * qmul;
    u32b packed = ((u32b)f2b(oe)) | (((u32b)f2b(oo)) << 16);
    *(u32b*)(out + (size_t)row * DMODEL + 2 * p) = packed;
  }
}

// ---------------- segment descriptors ----------------
struct Seg { const float* bias; float* outF; u16b* outB; };
struct Segs { Seg s[3]; };

// ---------------- 128x128 GEMM, 3-buffer counted-vmcnt pipeline ----------------
// EPI: 3 = gelu->bf16 (bias); 5 = split-K partial contiguous (outF + z*M*N);
//      6 = split-K partial two-pointer (z ? outF2 : outF)
template<int EPI>
__global__ __launch_bounds__(256, 2) void gemm_bt(
    const u16b* __restrict__ A, const u16b* __restrict__ BT,
    const float* __restrict__ bias, float* __restrict__ outF,
    float* __restrict__ outF2, u16b* __restrict__ outB,
    int M, int N, int K, int kLen)
{
  __shared__ char Ls[3][16384];
  const int tid = threadIdx.x, lane = tid & 63, wid = tid >> 6;
  const int nwg = gridDim.x * gridDim.y;
  const int swz = xcd_swz(blockIdx.x + gridDim.x * blockIdx.y, nwg);
  const int bm = (swz % gridDim.x) * 128, bn = (swz / gridDim.x) * 128;
  const int kbase = blockIdx.z * kLen;
  const int wm = (wid >> 1) * 64, wn = (wid & 1) * 64;
  v4f acc[4][4] = {};

  const u16b* pA[2]; const u16b* pB[2];
  #pragma unroll
  for (int c = 0; c < 2; ++c){
    int row = c * 64 + (tid >> 2);
    int col = (tid & 3) ^ swz4(row);
    pA[c] = A + (size_t)min(bm + row, M - 1) * K + kbase + col * 8;
    pB[c] = BT + (size_t)(bn + row) * K + kbase + col * 8;
  }
  auto stage = [&](int b){
    char* Lb = Ls[b];
    #pragma unroll
    for (int c = 0; c < 2; ++c){
      gl_lds16(pA[c], Lb + (c * 256 + tid) * 16);
      gl_lds16(pB[c], Lb + 8192 + (c * 256 + tid) * 16);
      pA[c] += 32; pB[c] += 32;
    }
  };

  const int chk = lane >> 4, qr = lane & 15;
  int offA[4], offB[4];
  #pragma unroll
  for (int f = 0; f < 4; ++f){
    int ra = wm + f * 16 + qr;
    offA[f] = ra * 64 + ((chk ^ swz4(ra)) * 16);
    int rb = wn + f * 16 + qr;
    offB[f] = 8192 + rb * 64 + ((chk ^ swz4(rb)) * 16);
  }

  const int nt = kLen / 32;
  stage(0); stage(1);
  int s = 0, sp = 2;
  for (int t = 0; t < nt; ++t){
    if (t + 1 < nt) asm volatile("s_waitcnt vmcnt(4)" ::: "memory");
    else            asm volatile("s_waitcnt vmcnt(0)" ::: "memory");
    __builtin_amdgcn_s_barrier();
    if (t + 2 < nt) stage(sp);
    char* Lb = Ls[s];
    v8s af[4], bfr[4];
    #pragma unroll
    for (int f = 0; f < 4; ++f){
      af[f] = *(const v8s*)(Lb + offA[f]);
      bfr[f] = *(const v8s*)(Lb + offB[f]);
    }
    __builtin_amdgcn_s_setprio(1);
    #pragma unroll
    for (int i = 0; i < 4; ++i)
      #pragma unroll
      for (int j = 0; j < 4; ++j)
        acc[i][j] = __builtin_amdgcn_mfma_f32_16x16x32_bf16(af[i], bfr[j], acc[i][j], 0, 0, 0);
    __builtin_amdgcn_s_setprio(0);
    s = (s == 2) ? 0 : s + 1;
    sp = (sp == 2) ? 0 : sp + 1;
  }
  const int rr = lane >> 4;
  float* op6 = (EPI == 6) ? (blockIdx.z ? outF2 : outF) : outF;
  #pragma unroll
  for (int i = 0; i < 4; ++i){
    #pragma unroll
    for (int j = 0; j < 4; ++j){
      int n = bn + wn + j * 16 + qr;
      float bv = (EPI == 3) ? bias[n] : 0.f;
      #pragma unroll
      for (int r = 0; r < 4; ++r){
        int m = bm + wm + i * 16 + rr * 4 + r;
        if (m < M){
          float val = acc[i][j][r] + bv;
          size_t idx = (size_t)m * N + n;
          if (EPI == 3){
            float t3 = val * val * val;
            float g = val / (1.f + __expf(-1.5957691216057308f * (val + 0.044715f * t3)));
            outB[idx] = f2b(g);
          } else if (EPI == 5){
            outF[(size_t)blockIdx.z * M * N + idx] = val;
          } else {
            op6[idx] = val;
          }
        }
      }
    }
  }
}

// ---------------- segmented 128^2 GEMM (QKV / ca K/V fused) ----------------
__global__ __launch_bounds__(256, 2) void gemm_seg(
    const u16b* __restrict__ A, const u16b* __restrict__ BT,
    Segs segs, int M, int N, int K)
{
  __shared__ char Ls[3][16384];
  const int tid = threadIdx.x, lane = tid & 63, wid = tid >> 6;
  const int nwg = gridDim.x * gridDim.y;
  const int swz = xcd_swz(blockIdx.x + gridDim.x * blockIdx.y, nwg);
  const int bm = (swz % gridDim.x) * 128, bn = (swz / gridDim.x) * 128;
  const int wm = (wid >> 1) * 64, wn = (wid & 1) * 64;
  v4f acc[4][4] = {};

  const u16b* pA[2]; const u16b* pB[2];
  #pragma unroll
  for (int c = 0; c < 2; ++c){
    int row = c * 64 + (tid >> 2);
    int col = (tid & 3) ^ swz4(row);
    pA[c] = A + (size_t)min(bm + row, M - 1) * K + col * 8;
    pB[c] = BT + (size_t)(bn + row) * K + col * 8;
  }
  auto stage = [&](int b){
    char* Lb = Ls[b];
    #pragma unroll
    for (int c = 0; c < 2; ++c){
      gl_lds16(pA[c], Lb + (c * 256 + tid) * 16);
      gl_lds16(pB[c], Lb + 8192 + (c * 256 + tid) * 16);
      pA[c] += 32; pB[c] += 32;
    }
  };

  const int chk = lane >> 4, qr = lane & 15;
  int offA[4], offB[4];
  #pragma unroll
  for (int f = 0; f < 4; ++f){
    int ra = wm + f * 16 + qr;
    offA[f] = ra * 64 + ((chk ^ swz4(ra)) * 16);
    int rb = wn + f * 16 + qr;
    offB[f] = 8192 + rb * 64 + ((chk ^ swz4(rb)) * 16);
  }

  const int nt = K / 32;
  stage(0); stage(1);
  int s = 0, sp = 2;
  for (int t = 0; t < nt; ++t){
    if (t + 1 < nt) asm volatile("s_waitcnt vmcnt(4)" ::: "memory");
    else            asm volatile("s_waitcnt vmcnt(0)" ::: "memory");
    __builtin_amdgcn_s_barrier();
    if (t + 2 < nt) stage(sp);
    char* Lb = Ls[s];
    v8s af[4], bfr[4];
    #pragma unroll
    for (int f = 0; f < 4; ++f){
      af[f] = *(const v8s*)(Lb + offA[f]);
      bfr[f] = *(const v8s*)(Lb + offB[f]);
    }
    __builtin_amdgcn_s_setprio(1);
    #pragma unroll
    for (int i = 0; i < 4; ++i)
      #pragma unroll
      for (int j = 0; j < 4; ++j)
        acc[i][j] = __builtin_amdgcn_mfma_f32_16x16x32_bf16(af[i], bfr[j], acc[i][j], 0, 0, 0);
    __builtin_amdgcn_s_setprio(0);
    s = (s == 2) ? 0 : s + 1;
    sp = (sp == 2) ? 0 : sp + 1;
  }
  const int seg = bn / 1536;
  const Seg sg = segs.s[seg];
  const int rr = lane >> 4;
  #pragma unroll
  for (int i = 0; i < 4; ++i){
    #pragma unroll
    for (int j = 0; j < 4; ++j){
      int nloc = bn - seg * 1536 + wn + j * 16 + qr;
      float bv = sg.bias[nloc];
      #pragma unroll
      for (int r = 0; r < 4; ++r){
        int m = bm + wm + i * 16 + rr * 4 + r;
        if (m < M){
          float val = acc[i][j][r] + bv;
          size_t idx = (size_t)m * 1536 + nloc;
          if (sg.outB) sg.outB[idx] = f2b(val);
          else sg.outF[idx] = val;
        }
      }
    }
  }
}

// ---------------- split-K x2 reduce: out = res? + gate? * (p0+p1+bias) ----------------
__global__ __launch_bounds__(256) void red2(const float* __restrict__ p0,
                                            const float* __restrict__ p1,
                                            const float* __restrict__ res,
                                            const float* __restrict__ gate,
                                            const float* __restrict__ bias,
                                            float* __restrict__ out, int total){
  int i4 = blockIdx.x * 256 + threadIdx.x;
  if (i4 * 4 >= total) return;
  int base = i4 * 4, n = base % DMODEL;
  float4 a = *(const float4*)(p0 + base);
  float4 b = *(const float4*)(p1 + base);
  float4 bv = *(const float4*)(bias + n);
  float gx = 1.f, gy = 1.f, gz = 1.f, gw = 1.f;
  if (gate){ float4 g = *(const float4*)(gate + n); gx = g.x; gy = g.y; gz = g.z; gw = g.w; }
  float rx = 0.f, ry = 0.f, rz = 0.f, rw = 0.f;
  if (res){ float4 r = *(const float4*)(res + base); rx = r.x; ry = r.y; rz = r.z; rw = r.w; }
  float4 o;
  o.x = rx + gx * (a.x + b.x + bv.x);
  o.y = ry + gy * (a.y + b.y + bv.y);
  o.z = rz + gz * (a.z + b.z + bv.z);
  o.w = rw + gw * (a.w + b.w + bv.w);
  *(float4*)(out + base) = o;
}

// ---------------- flash attention: KVBLK=64, single KV buffer, no key-split ----------------
__global__ __launch_bounds__(256, 4) void flash_attn(
    const u16b* __restrict__ Q, const u16b* __restrict__ Kp,
    const u16b* __restrict__ Vt, u16b* __restrict__ O,
    int Sq, int Sk, int Spad)
{
  __shared__ char KV[32768];
  __shared__ char Pall[8192];
  const int tid = threadIdx.x, lane = tid & 63, wid = tid >> 6;
  const int h = blockIdx.y;
  const int q0 = blockIdx.x * 64 + wid * 16;
  const int qq = lane & 15, cc = lane >> 4;
  char* Kb = KV; char* Vb = KV + 16384;
  char* Pb = Pall + wid * 2048;

  v8s qf[4];
  {
    int qrow = min(q0 + qq, Sq - 1);
    const u16b* qp = Q + (size_t)qrow * DMODEL + h * HDIM + cc * 8;
    #pragma unroll
    for (int ks = 0; ks < 4; ++ks) qf[ks] = *(const v8s*)(qp + ks * 32);
  }

  auto stage = [&](int kb0){
    #pragma unroll
    for (int c = 0; c < 4; ++c){
      int seg = wid * 4 + c;
      int g = seg * 64 + lane;
      int krow = g >> 4, kcol = (g & 15) ^ (krow & 7);
      gl_lds16(Kp + (size_t)min(kb0 + krow, Sk - 1) * DMODEL + h * HDIM + kcol * 8,
               Kb + seg * 1024);
      int vrow = g >> 3, vcol = (g & 7) ^ (vrow & 7);
      gl_lds16(Vt + ((size_t)h * HDIM + vrow) * Spad + kb0 + vcol * 8,
               Vb + seg * 1024);
    }
  };

  float mrun = -1e30f, lrun = 0.f;
  v4f oacc[8] = {};
  const int nt = (Sk + 63) >> 6;

  for (int t = 0; t < nt; ++t){
    int kb0 = t << 6;
    stage(kb0);
    __syncthreads();
    v4f sc[4];
    __builtin_amdgcn_s_setprio(1);
    #pragma unroll
    for (int sub = 0; sub < 4; ++sub){
      v4f sa = {0.f, 0.f, 0.f, 0.f};
      int row = sub * 16 + qq;
      #pragma unroll
      for (int ks = 0; ks < 4; ++ks){
        v8s kf = *(const v8s*)(Kb + row * 256 + (((ks * 4 + cc) ^ (row & 7)) * 16));
        sa = __builtin_amdgcn_mfma_f32_16x16x32_bf16(kf, qf[ks], sa, 0, 0, 0);
      }
      sc[sub] = sa;
    }
    __builtin_amdgcn_s_setprio(0);
    if (kb0 + 64 > Sk){
      #pragma unroll
      for (int sub = 0; sub < 4; ++sub)
        #pragma unroll
        for (int r = 0; r < 4; ++r)
          if (kb0 + sub * 16 + cc * 4 + r >= Sk) sc[sub][r] = -1e30f;
    }
    float m01 = fmaxf(fmaxf(sc[0][0], sc[0][1]), fmaxf(sc[0][2], sc[0][3]));
    float m23 = fmaxf(fmaxf(sc[1][0], sc[1][1]), fmaxf(sc[1][2], sc[1][3]));
    float m45 = fmaxf(fmaxf(sc[2][0], sc[2][1]), fmaxf(sc[2][2], sc[2][3]));
    float m67 = fmaxf(fmaxf(sc[3][0], sc[3][1]), fmaxf(sc[3][2], sc[3][3]));
    float pmax = fmaxf(fmaxf(m01, m23), fmaxf(m45, m67));
    pmax = fmaxf(pmax, __shfl_xor(pmax, 16));
    pmax = fmaxf(pmax, __shfl_xor(pmax, 32));
    if (!__all(pmax <= mrun + 11.54f)){
      float mnew = fmaxf(mrun, pmax);
      float alpha = exp2f(mrun - mnew);
      mrun = mnew;
      float alr[4];
      #pragma unroll
      for (int r = 0; r < 4; ++r) alr[r] = __shfl(alpha, cc * 4 + r);
      #pragma unroll
      for (int f = 0; f < 8; ++f)
        #pragma unroll
        for (int r = 0; r < 4; ++r) oacc[f][r] *= alr[r];
      lrun *= alpha;
    }
    float csum = 0.f;
    #pragma unroll
    for (int sub = 0; sub < 4; ++sub){
      float s0 = 0.f, s1 = 0.f;
      #pragma unroll
      for (int r = 0; r < 4; r += 2){
        float p0 = exp2f(sc[sub][r] - mrun);
        float p1 = exp2f(sc[sub][r + 1] - mrun);
        sc[sub][r] = p0; sc[sub][r + 1] = p1;
        s0 += p0; s1 += p1;
      }
      csum += s0 + s1;
    }
    csum += __shfl_xor(csum, 16);
    csum += __shfl_xor(csum, 32);
    lrun += csum;
    #pragma unroll
    for (int sub = 0; sub < 4; ++sub){
      uint2 w2;
      w2.x = cvtpk(sc[sub][0], sc[sub][1]);
      w2.y = cvtpk(sc[sub][2], sc[sub][3]);
      int gI = sub * 2 + (cc >> 1);
      *(uint2*)(Pb + qq * 128 + ((gI ^ (qq & 7)) * 16) + (cc & 1) * 8) = w2;
    }
    v8s pf0 = *(const v8s*)(Pb + qq * 128 + (((cc) ^ (qq & 7)) * 16));
    v8s pf1 = *(const v8s*)(Pb + qq * 128 + (((4 + cc) ^ (qq & 7)) * 16));
    __builtin_amdgcn_s_setprio(1);
    #pragma unroll
    for (int hdb = 0; hdb < 8; ++hdb){
      int row = hdb * 16 + qq;
      v8s vf0 = *(const v8s*)(Vb + row * 128 + (((cc) ^ (row & 7)) * 16));
      v8s vf1 = *(const v8s*)(Vb + row * 128 + (((4 + cc) ^ (row & 7)) * 16));
      oacc[hdb] = __builtin_amdgcn_mfma_f32_16x16x32_bf16(pf0, vf0, oacc[hdb], 0, 0, 0);
      oacc[hdb] = __builtin_amdgcn_mfma_f32_16x16x32_bf16(pf1, vf1, oacc[hdb], 0, 0, 0);
    }
    __builtin_amdgcn_s_setprio(0);
    __syncthreads();
  }

  float linv = 1.f / lrun;
  float lr[4];
  #pragma unroll
  for (int r = 0; r < 4; ++r) lr[r] = __shfl(linv, cc * 4 + r);
  #pragma unroll
  for (int hdb = 0; hdb < 8; ++hdb)
    #pragma unroll
    for (int r = 0; r < 4; ++r){
      int qrow = q0 + cc * 4 + r;
      if (qrow < Sq)
        O[(size_t)qrow * DMODEL + h * HDIM + hdb * 16 + qq] = f2b(oacc[hdb][r] * lr[r]);
    }
}

// ---------------- host launch ----------------
extern "C" void kernel_launch(void* const* d_in, const int* in_sizes, int n_in,
                              void* d_out, int out_size, void* d_ws, size_t ws_size,
                              hipStream_t stream){
  (void)in_sizes; (void)n_in; (void)out_size; (void)ws_size;
  const float* x     = (const float*)d_in[0];
  const float* ctx   = (const float*)d_in[1];
  const float* t_mod = (const float*)d_in[2];
  const float* ropec = (const float*)d_in[3];
  const float* ropes = (const float*)d_in[4];
  const float* modu  = (const float*)d_in[5];
  const float* sa_qw = (const float*)d_in[6];  const float* sa_qb = (const float*)d_in[7];
  const float* sa_kw = (const float*)d_in[8];  const float* sa_kb = (const float*)d_in[9];
  const float* sa_vw = (const float*)d_in[10]; const float* sa_vb = (const float*)d_in[11];
  const float* sa_ow = (const float*)d_in[12]; const float* sa_ob = (const float*)d_in[13];
  const float* sa_nq = (const float*)d_in[14]; const float* sa_nk = (const float*)d_in[15];
  const float* ca_qw = (const float*)d_in[16]; const float* ca_qb = (const float*)d_in[17];
  const float* ca_kw = (const float*)d_in[18]; const float* ca_kb = (const float*)d_in[19];
  const float* ca_vw = (const float*)d_in[20]; const float* ca_vb = (const float*)d_in[21];
  const float* ca_ow = (const float*)d_in[22]; const float* ca_ob = (const float*)d_in[23];
  const float* ca_nq = (const float*)d_in[24]; const float* ca_nk = (const float*)d_in[25];
  const float* n3w   = (const float*)d_in[26]; const float* n3b   = (const float*)d_in[27];
  const float* fw1   = (const float*)d_in[28]; const float* fb1   = (const float*)d_in[29];
  const float* fw2   = (const float*)d_in[30]; const float* fb2   = (const float*)d_in[31];
  float* out = (float*)d_out;

  const float QSCALE = 0.08838834764831845f * 1.4426950408889634f;

  char* wsp = (char*)d_ws;
  size_t off = 0;
  auto alloc = [&](size_t b){ void* p = wsp + off; off += (b + 255) & ~(size_t)255; return p; };
  const size_t WW = (size_t)DMODEL * DMODEL * 2;
  float* modc = (float*)alloc(6 * DMODEL * 4);
  u16b* w1T   = (u16b*)alloc((size_t)FFND * DMODEL * 2);
  u16b* w2T   = (u16b*)alloc((size_t)DMODEL * FFND * 2);
  u16b* h_bf  = (u16b*)alloc((size_t)S_LEN * DMODEL * 2);
  float* pre0 = (float*)alloc((size_t)S_LEN * DMODEL * 4);
  size_t region0 = off;
  u16b* sa_qkvT = (u16b*)alloc(3 * WW);
  u16b* sa_owT  = (u16b*)alloc(WW);
  u16b* ca_qwT  = (u16b*)alloc(WW);
  u16b* ca_kvT  = (u16b*)alloc(2 * WW);
  u16b* ca_owT  = (u16b*)alloc(WW);
  float* x2    = (float*)alloc((size_t)S_LEN * DMODEL * 4);
  float* pre2  = (float*)alloc((size_t)LCTX * DMODEL * 4);
  u16b* qb     = (u16b*)alloc((size_t)S_LEN * DMODEL * 2);   // qb..kb = 22.1MB f32-partial span
  u16b* kb     = (u16b*)alloc((size_t)S_LEN * DMODEL * 2);
  u16b* vb     = (u16b*)alloc((size_t)S_LEN * DMODEL * 2);   // vb..ab = 22.1MB f32-partial span
  u16b* ab     = (u16b*)alloc((size_t)S_LEN * DMODEL * 2);
  u16b* ctxb   = (u16b*)alloc((size_t)LCTX * DMODEL * 2);
  u16b* k2b    = (u16b*)alloc((size_t)LCTX * DMODEL * 2);
  u16b* v2b    = (u16b*)alloc((size_t)LCTX * DMODEL * 2);
  u16b* vts    = (u16b*)alloc((size_t)NH * HDIM * SPAD_SELF * 2);  // self V^T; later ca_q bf16 (dead after self flash)
  u16b* vtc    = (u16b*)alloc((size_t)NH * HDIM * LCTX * 2);
  u16b* fmid = (u16b*)(wsp + region0);
  float* fpart = (float*)(wsp + region0 + (size_t)S_LEN * FFND * 2);

  add_vec<<<36, 256, 0, stream>>>(modu, t_mod, modc, 6 * DMODEL);

  WJobs jobs; int t = 0;
  auto addjob = [&](int i, const float* w_, u16b* wt, int K, int N){
    jobs.j[i].W = w_; jobs.j[i].WT = wt; jobs.j[i].K = K; jobs.j[i].N = N; jobs.j[i].t0 = t;
    t += (K / 32) * (N / 32);
  };
  addjob(0, sa_qw, sa_qkvT, DMODEL, DMODEL);
  addjob(1, sa_kw, sa_qkvT + (size_t)DMODEL * DMODEL, DMODEL, DMODEL);
  addjob(2, sa_vw, sa_qkvT + (size_t)2 * DMODEL * DMODEL, DMODEL, DMODEL);
  addjob(3, sa_ow, sa_owT, DMODEL, DMODEL);
  addjob(4, ca_qw, ca_qwT, DMODEL, DMODEL);
  addjob(5, ca_kw, ca_kvT, DMODEL, DMODEL);
  addjob(6, ca_vw, ca_kvT + (size_t)DMODEL * DMODEL, DMODEL, DMODEL);
  addjob(7, ca_ow, ca_owT, DMODEL, DMODEL);
  addjob(8, fw1, w1T, DMODEL, FFND);
  addjob(9, fw2, w2T, FFND, DMODEL);
  wconv<<<t, 256, 0, stream>>>(jobs);

  f2b_kernel<<<(LCTX * DMODEL) / 256, 256, 0, stream>>>(ctx, ctxb, LCTX * DMODEL);

  const int RED_G = (S_LEN * DMODEL / 4 + 255) / 256;

  // ---- self attention branch ----
  ln_mod<<<S_LEN, 256, 0, stream>>>(x, modc + DMODEL, modc, 1.f, h_bf);
  {
    Segs sg;
    sg.s[0] = { sa_qb, pre0, nullptr };
    sg.s[1] = { sa_kb, x2,   nullptr };
    sg.s[2] = { sa_vb, nullptr, vb   };
    gemm_seg<<<dim3(29, 36), 256, 0, stream>>>(h_bf, sa_qkvT, sg, S_LEN, 3 * DMODEL, DMODEL);
  }
  rms_rope2<<<dim3(S_LEN, 2), 256, 0, stream>>>(pre0, x2, sa_nq, sa_nk, ropec, ropes, QSCALE, qb, kb);
  vtrans<<<dim3(SPAD_SELF / 32, 12), 256, 0, stream>>>(vb, vts, S_LEN, SPAD_SELF);
  flash_attn<<<dim3(57, 12), 256, 0, stream>>>(qb, kb, vts, ab, S_LEN, S_LEN, SPAD_SELF);
  // sa o-proj split-K x2: partials -> pre0 (dead) and qb..kb span (dead)
  gemm_bt<6><<<dim3(29, 12, 2), 256, 0, stream>>>(ab, sa_owT, nullptr,
      (float*)pre0, (float*)qb, nullptr, S_LEN, DMODEL, DMODEL, 768);
  // fused: x2 = x + g_msa*(o + sa_ob); h_bf = LN(x2)*n3w + n3b
  red2_ln<<<S_LEN, 256, 0, stream>>>((const float*)pre0, (const float*)qb,
      x, modc + 2 * DMODEL, sa_ob, n3w, n3b, 0.f, x2, h_bf);

  // ---- cross attention branch ----
  // ca_q split-K x2: partials -> qb..kb (dead) and vb..ab (dead); fused reduce+RMS -> vts (dead)
  gemm_bt<6><<<dim3(29, 12, 2), 256, 0, stream>>>(h_bf, ca_qwT, nullptr,
      (float*)qb, (float*)vb, nullptr, S_LEN, DMODEL, DMODEL, 768);
  red2_rms<<<S_LEN, 256, 0, stream>>>((const float*)qb, (const float*)vb,
      ca_qb, ca_nq, QSCALE, vts);
  {
    Segs sg;
    sg.s[0] = { ca_kb, pre2, nullptr };
    sg.s[1] = { ca_vb, nullptr, v2b  };
    sg.s[2] = { ca_vb, nullptr, v2b  };
    gemm_seg<<<dim3(4, 24), 256, 0, stream>>>(ctxb, ca_kvT, sg, LCTX, 2 * DMODEL, DMODEL);
  }
  rms_rope<<<LCTX, 256, 0, stream>>>(pre2, ca_nk, nullptr, nullptr, 1.f, k2b);
  vtrans<<<dim3(16, 12), 256, 0, stream>>>(v2b, vtc, LCTX, LCTX);
  flash_attn<<<dim3(57, 12), 256, 0, stream>>>(vts, k2b, vtc, ab, S_LEN, LCTX, LCTX);
  // ca o-proj split-K x2: partials -> qb..kb (dead) and sa_qkvT region (dead)
  gemm_bt<6><<<dim3(29, 12, 2), 256, 0, stream>>>(ab, ca_owT, nullptr,
      (float*)qb, (float*)sa_qkvT, nullptr, S_LEN, DMODEL, DMODEL, 768);
  // fused: pre0 = x2 + (o + ca_ob); h_bf = LN(pre0)*(1+sc_mlp) + sh_mlp
  red2_ln<<<S_LEN, 256, 0, stream>>>((const float*)qb, (const float*)sa_qkvT,
      x2, nullptr, ca_ob, modc + 4 * DMODEL, modc + 3 * DMODEL, 1.f, pre0, h_bf);

  // ---- FFN ----
  gemm_bt<3><<<dim3(29, 70), 256, 0, stream>>>(h_bf, w1T, fb1,
      nullptr, nullptr, fmid, S_LEN, FFND, DMODEL, DMODEL);
  gemm_bt<5><<<dim3(29, 12, 2), 256, 0, stream>>>(fmid, w2T, nullptr,
      fpart, nullptr, nullptr, S_LEN, DMODEL, FFND, FFND / 2);
  red2<<<RED_G, 256, 0, stream>>>(fpart, fpart + (size_t)S_LEN * DMODEL,
      pre0, modc + 5 * DMODEL, fb2, out, S_LEN * DMODEL);
}